// Round 1
// baseline (446.667 us; speedup 1.0000x reference)
//
#include <hip/hip_runtime.h>
#include <hip/hip_bf16.h>

typedef __bf16 bf16;
typedef __attribute__((ext_vector_type(8))) __bf16 bf16x8;
typedef __attribute__((ext_vector_type(4))) __bf16 bf16x4;
typedef __attribute__((ext_vector_type(4))) float f32x4;

#define MFMA16(a, b, c) __builtin_amdgcn_mfma_f32_16x16x32_bf16((a), (b), (c), 0, 0, 0)

__device__ inline void gload_lds16(const bf16* g, bf16* l) {
  __builtin_amdgcn_global_load_lds(
      (const __attribute__((address_space(1))) void*)g,
      (__attribute__((address_space(3))) void*)l, 16, 0, 0);
}

// ---------------- f32 -> bf16 conversion ----------------
__global__ void cvt_f32_bf16(const float* __restrict__ in, bf16* __restrict__ out, int n4) {
  int stride = gridDim.x * blockDim.x;
  for (int i = blockIdx.x * blockDim.x + threadIdx.x; i < n4; i += stride) {
    float4 v = reinterpret_cast<const float4*>(in)[i];
    bf16x4 o = {(bf16)v.x, (bf16)v.y, (bf16)v.z, (bf16)v.w};
    reinterpret_cast<bf16x4*>(out)[i] = o;
  }
}

// ---------------- GEMM: C[M,N] = A[M,K] * W[N,K]^T + bias ----------------
// 128x128 tile, BK=32, 4 waves (2x2), acc 4x4 frags of 16x16.
// blockIdx.z selects weight/output slice (QKV fusion); bias picked by z.
template <bool OUT_BF16>
__global__ __launch_bounds__(256) void gemm_bt(
    const bf16* __restrict__ A, const bf16* __restrict__ W,
    const float* __restrict__ b0, const float* __restrict__ b1, const float* __restrict__ b2,
    float* __restrict__ Cf, bf16* __restrict__ Cb,
    int M, int N, int K) {
  const int z = blockIdx.z;
  const bf16* Wz = W + (size_t)z * N * K;
  const float* bias = (z == 0) ? b0 : (z == 1 ? b1 : b2);

  __shared__ alignas(16) bf16 As[128 * 32];
  __shared__ alignas(16) bf16 Bs[128 * 32];

  const int tid = threadIdx.x;
  const int wave = tid >> 6, lane = tid & 63;
  const int lr = lane & 15, lg = lane >> 4;
  const int wr = wave >> 1, wc = wave & 1;
  const int m0 = blockIdx.y * 128, n0 = blockIdx.x * 128;

  f32x4 acc[4][4] = {};

  for (int k0 = 0; k0 < K; k0 += 32) {
    __syncthreads();
#pragma unroll
    for (int j = 0; j < 2; ++j) {
      int cb = (j * 4 + wave) * 64;  // wave-uniform chunk base
      int c = cb + lane;
      int row = c >> 2, x = c & 3;
      gload_lds16(&A[(size_t)(m0 + row) * K + k0 + x * 8], &As[cb * 8]);
      gload_lds16(&Wz[(size_t)(n0 + row) * K + k0 + x * 8], &Bs[cb * 8]);
    }
    __syncthreads();
    bf16x8 af[4], bfr[4];
#pragma unroll
    for (int m = 0; m < 4; ++m)
      af[m] = *reinterpret_cast<const bf16x8*>(&As[(wr * 64 + m * 16 + lr) * 32 + lg * 8]);
#pragma unroll
    for (int n = 0; n < 4; ++n)
      bfr[n] = *reinterpret_cast<const bf16x8*>(&Bs[(wc * 64 + n * 16 + lr) * 32 + lg * 8]);
#pragma unroll
    for (int m = 0; m < 4; ++m)
#pragma unroll
      for (int n = 0; n < 4; ++n)
        acc[m][n] = MFMA16(af[m], bfr[n], acc[m][n]);
  }

#pragma unroll
  for (int m = 0; m < 4; ++m) {
#pragma unroll
    for (int n = 0; n < 4; ++n) {
#pragma unroll
      for (int i = 0; i < 4; ++i) {
        int row = m0 + wr * 64 + m * 16 + lg * 4 + i;
        int col = n0 + wc * 64 + n * 16 + lr;
        float v = acc[m][n][i] + bias[col];
        if constexpr (OUT_BF16)
          (Cb + (size_t)z * M * N)[(size_t)row * N + col] = (bf16)v;
        else
          Cf[(size_t)row * N + col] = v;
      }
    }
  }
}

// ---------------- causal flash attention ----------------
// grid: (S/64, H, B), 256 threads. Wave w owns q rows [q0+16w, q0+16w+16).
__global__ __launch_bounds__(256) void attn(
    const bf16* __restrict__ Q, const bf16* __restrict__ K,
    const bf16* __restrict__ V, bf16* __restrict__ Y) {
  constexpr int S = 4096, D = 768;
  const int bq = blockIdx.x;
  const int h = blockIdx.y;
  const int bb = blockIdx.z;
  const int tid = threadIdx.x, wave = tid >> 6, lane = tid & 63;
  const int lr = lane & 15, lg = lane >> 4;
  const int q0 = bq * 64;

  __shared__ alignas(16) bf16 Ks[2][64][32];   // [ks][krow][kk]
  __shared__ alignas(16) bf16 Vt[2][64][32];   // [ks][d][kk] = V[ks*32+kk][d]
  __shared__ alignas(16) bf16 Ps[4][2][16][32];// [wave][ks][qrow][kk]

  const size_t head = (size_t)bb * S * D + (size_t)h * 64;

  const int qrow = q0 + wave * 16 + lr;
  bf16x8 qf[2];
  qf[0] = *reinterpret_cast<const bf16x8*>(&Q[head + (size_t)qrow * D + lg * 8]);
  qf[1] = *reinterpret_cast<const bf16x8*>(&Q[head + (size_t)qrow * D + 32 + lg * 8]);

  f32x4 oacc[4] = {};
  float mrun[4], lrun[4];
#pragma unroll
  for (int i = 0; i < 4; ++i) { mrun[i] = -1e30f; lrun[i] = 0.f; }
  const float scale = 0.125f;

  for (int kt = 0; kt <= bq; ++kt) {
    const int kv0 = kt * 64;
    __syncthreads();
    // stage K: 512 x 16B chunks, linear LDS dest
#pragma unroll
    for (int j = 0; j < 2; ++j) {
      int cb = (j * 4 + wave) * 64;
      int c = cb + lane;
      int s = c >> 8, r = (c >> 2) & 63, x = c & 3;
      gload_lds16(&K[head + (size_t)(kv0 + r) * D + s * 32 + x * 8], &Ks[0][0][0] + cb * 8);
    }
    // stage V transposed (reg staging + scalar ds writes)
#pragma unroll
    for (int j = 0; j < 2; ++j) {
      int c = tid * 2 + j;            // 0..511
      int r = c >> 3;                 // key pos 0..63
      int x = c & 7;                  // which 8-col chunk of d
      bf16x8 vv = *reinterpret_cast<const bf16x8*>(&V[head + (size_t)(kv0 + r) * D + x * 8]);
      int s = r >> 5, kk = r & 31;
#pragma unroll
      for (int e = 0; e < 8; ++e) Vt[s][x * 8 + e][kk] = vv[e];
    }
    __syncthreads();

    // S = Q K^T
    f32x4 sacc[4] = {};
#pragma unroll
    for (int n = 0; n < 4; ++n)
#pragma unroll
      for (int ks = 0; ks < 2; ++ks) {
        bf16x8 kf = *reinterpret_cast<const bf16x8*>(&Ks[ks][n * 16 + lr][lg * 8]);
        sacc[n] = MFMA16(qf[ks], kf, sacc[n]);
      }

    // scale + causal mask
    float sv[4][4];
#pragma unroll
    for (int n = 0; n < 4; ++n) {
      int col = kv0 + n * 16 + lr;
#pragma unroll
      for (int i = 0; i < 4; ++i) {
        int row = q0 + wave * 16 + lg * 4 + i;
        sv[n][i] = (col > row) ? -1e30f : sacc[n][i] * scale;
      }
    }

    // online softmax (row stats live in the 16-lane group, per reg i)
    float alpha[4], tsum[4];
#pragma unroll
    for (int i = 0; i < 4; ++i) {
      float mx = fmaxf(fmaxf(sv[0][i], sv[1][i]), fmaxf(sv[2][i], sv[3][i]));
      mx = fmaxf(mx, __shfl_xor(mx, 1));
      mx = fmaxf(mx, __shfl_xor(mx, 2));
      mx = fmaxf(mx, __shfl_xor(mx, 4));
      mx = fmaxf(mx, __shfl_xor(mx, 8));
      float mnew = fmaxf(mrun[i], mx);
      alpha[i] = __expf(mrun[i] - mnew);
      mrun[i] = mnew;
      tsum[i] = 0.f;
    }
#pragma unroll
    for (int n = 0; n < 4; ++n)
#pragma unroll
      for (int i = 0; i < 4; ++i) {
        float p = __expf(sv[n][i] - mrun[i]);
        tsum[i] += p;
        Ps[wave][n >> 1][lg * 4 + i][(n & 1) * 16 + lr] = (bf16)p;
      }
#pragma unroll
    for (int i = 0; i < 4; ++i) {
      float su = tsum[i];
      su += __shfl_xor(su, 1);
      su += __shfl_xor(su, 2);
      su += __shfl_xor(su, 4);
      su += __shfl_xor(su, 8);
      lrun[i] = lrun[i] * alpha[i] + su;
    }
#pragma unroll
    for (int f = 0; f < 4; ++f)
#pragma unroll
      for (int i = 0; i < 4; ++i) oacc[f][i] *= alpha[i];

    // O += P V  (P re-fragmented via per-wave LDS; V read from transposed tile)
#pragma unroll
    for (int ks = 0; ks < 2; ++ks) {
      bf16x8 pf = *reinterpret_cast<const bf16x8*>(&Ps[wave][ks][lr][lg * 8]);
#pragma unroll
      for (int f = 0; f < 4; ++f) {
        bf16x8 vf = *reinterpret_cast<const bf16x8*>(&Vt[ks][f * 16 + lr][lg * 8]);
        oacc[f] = MFMA16(pf, vf, oacc[f]);
      }
    }
  }

#pragma unroll
  for (int f = 0; f < 4; ++f)
#pragma unroll
    for (int i = 0; i < 4; ++i) {
      int row = q0 + wave * 16 + lg * 4 + i;
      float v = oacc[f][i] / lrun[i];
      Y[head + (size_t)row * D + f * 16 + lr] = (bf16)v;
    }
}

// ---------------- launcher ----------------
extern "C" void kernel_launch(void* const* d_in, const int* in_sizes, int n_in,
                              void* d_out, int out_size, void* d_ws, size_t ws_size,
                              hipStream_t stream) {
  const float* x  = (const float*)d_in[0];
  const float* Wq = (const float*)d_in[1];
  const float* bq = (const float*)d_in[2];
  const float* Wk = (const float*)d_in[3];
  const float* bk = (const float*)d_in[4];
  const float* Wv = (const float*)d_in[5];
  const float* bv = (const float*)d_in[6];
  const float* Wo = (const float*)d_in[7];
  const float* bo = (const float*)d_in[8];
  float* out = (float*)d_out;

  constexpr int Bx = 2, S = 4096, Dd = 768;
  constexpr int M = Bx * S;                   // 8192
  constexpr size_t XB = (size_t)M * Dd;       // 6291456 elems
  constexpr size_t WB = (size_t)Dd * Dd;      // 589824 elems

  char* ws = (char*)d_ws;
  bf16* xb = (bf16*)ws;                        // XB elems
  bf16* Wb = (bf16*)(ws + 2 * XB);             // 4*WB elems (Wq,Wk,Wv,Wo)
  bf16* Qb = (bf16*)(ws + 2 * XB + 8 * WB);    // XB
  bf16* Kb = Qb + XB;
  bf16* Vb = Kb + XB;
  bf16* Yb = Vb + XB;

  cvt_f32_bf16<<<2048, 256, 0, stream>>>(x, xb, (int)(XB / 4));
  cvt_f32_bf16<<<512, 256, 0, stream>>>(Wq, Wb + 0 * WB, (int)(WB / 4));
  cvt_f32_bf16<<<512, 256, 0, stream>>>(Wk, Wb + 1 * WB, (int)(WB / 4));
  cvt_f32_bf16<<<512, 256, 0, stream>>>(Wv, Wb + 2 * WB, (int)(WB / 4));
  cvt_f32_bf16<<<512, 256, 0, stream>>>(Wo, Wb + 3 * WB, (int)(WB / 4));

  // fused Q/K/V projections (z = 0,1,2), bf16 out
  gemm_bt<true><<<dim3(6, 64, 3), 256, 0, stream>>>(
      xb, Wb, bq, bk, bv, nullptr, Qb, M, Dd, Dd);

  // attention
  attn<<<dim3(S / 64, 12, Bx), 256, 0, stream>>>(Qb, Kb, Vb, Yb);

  // output projection, f32 out
  gemm_bt<false><<<dim3(6, 64, 1), 256, 0, stream>>>(
      Yb, Wb + 3 * WB, bo, bo, bo, out, nullptr, M, Dd, Dd);
}

// Round 2
// 400.554 us; speedup vs baseline: 1.1151x; 1.1151x over previous
//
#include <hip/hip_runtime.h>
#include <hip/hip_bf16.h>

typedef __bf16 bf16;
typedef __attribute__((ext_vector_type(8))) __bf16 bf16x8;
typedef __attribute__((ext_vector_type(4))) __bf16 bf16x4;
typedef __attribute__((ext_vector_type(4))) float f32x4;

#define MFMA16(a, b, c) __builtin_amdgcn_mfma_f32_16x16x32_bf16((a), (b), (c), 0, 0, 0)

__device__ __forceinline__ void gload_lds16(const bf16* g, bf16* l) {
  __builtin_amdgcn_global_load_lds(
      (const __attribute__((address_space(1))) void*)g,
      (__attribute__((address_space(3))) void*)l, 16, 0, 0);
}

// swizzled element offset inside a [rows][32] bf16 plane (64-B rows).
// chunk (16B) index ^= ((row>>1)^(row>>3))&3  -> max 2-way bank aliasing (free).
__device__ __forceinline__ int swz32(int row, int col) {
  int ch = ((col >> 3) ^ (row >> 1) ^ (row >> 3)) & 3;
  return row * 32 + ch * 8 + (col & 7);
}
__device__ __forceinline__ int swzkey(int row) { return ((row >> 1) ^ (row >> 3)) & 3; }

// ---------------- f32 -> bf16 conversion ----------------
__global__ void cvt_f32_bf16(const float* __restrict__ in, bf16* __restrict__ out, int n4) {
  int stride = gridDim.x * blockDim.x;
  for (int i = blockIdx.x * blockDim.x + threadIdx.x; i < n4; i += stride) {
    float4 v = reinterpret_cast<const float4*>(in)[i];
    bf16x4 o = {(bf16)v.x, (bf16)v.y, (bf16)v.z, (bf16)v.w};
    reinterpret_cast<bf16x4*>(out)[i] = o;
  }
}

// ---------------- GEMM: C[M,N] = A[M,K] * W[N,K]^T + bias ----------------
template <bool OUT_BF16>
__global__ __launch_bounds__(256) void gemm_bt(
    const bf16* __restrict__ A, const bf16* __restrict__ W,
    const float* __restrict__ b0, const float* __restrict__ b1, const float* __restrict__ b2,
    float* __restrict__ Cf, bf16* __restrict__ Cb,
    int M, int N, int K) {
  const int z = blockIdx.z;
  const bf16* Wz = W + (size_t)z * N * K;
  const float* bias = (z == 0) ? b0 : (z == 1 ? b1 : b2);

  __shared__ alignas(16) bf16 As[128 * 32];
  __shared__ alignas(16) bf16 Bs[128 * 32];

  const int tid = threadIdx.x;
  const int wave = tid >> 6, lane = tid & 63;
  const int lr = lane & 15, lg = lane >> 4;
  const int wr = wave >> 1, wc = wave & 1;
  const int m0 = blockIdx.y * 128, n0 = blockIdx.x * 128;

  f32x4 acc[4][4] = {};

  for (int k0 = 0; k0 < K; k0 += 32) {
    __syncthreads();
#pragma unroll
    for (int j = 0; j < 2; ++j) {
      int cb = (j * 4 + wave) * 64;  // wave-uniform chunk base
      int c = cb + lane;
      int row = c >> 2, x = c & 3;
      int xs = (x ^ swzkey(row)) & 3;  // pre-swizzled global source (rule #21)
      gload_lds16(&A[(size_t)(m0 + row) * K + k0 + xs * 8], &As[cb * 8]);
      gload_lds16(&Wz[(size_t)(n0 + row) * K + k0 + xs * 8], &Bs[cb * 8]);
    }
    __syncthreads();
    bf16x8 af[4], bfr[4];
#pragma unroll
    for (int m = 0; m < 4; ++m)
      af[m] = *reinterpret_cast<const bf16x8*>(&As[swz32(wr * 64 + m * 16 + lr, lg * 8)]);
#pragma unroll
    for (int n = 0; n < 4; ++n)
      bfr[n] = *reinterpret_cast<const bf16x8*>(&Bs[swz32(wc * 64 + n * 16 + lr, lg * 8)]);
    __builtin_amdgcn_s_setprio(1);
#pragma unroll
    for (int m = 0; m < 4; ++m)
#pragma unroll
      for (int n = 0; n < 4; ++n)
        acc[m][n] = MFMA16(af[m], bfr[n], acc[m][n]);
    __builtin_amdgcn_s_setprio(0);
  }

#pragma unroll
  for (int m = 0; m < 4; ++m) {
#pragma unroll
    for (int n = 0; n < 4; ++n) {
#pragma unroll
      for (int i = 0; i < 4; ++i) {
        int row = m0 + wr * 64 + m * 16 + lg * 4 + i;
        int col = n0 + wc * 64 + n * 16 + lr;
        float v = acc[m][n][i] + bias[col];
        if constexpr (OUT_BF16)
          (Cb + (size_t)z * M * N)[(size_t)row * N + col] = (bf16)v;
        else
          Cf[(size_t)row * N + col] = v;
      }
    }
  }
}

// ---------------- causal flash attention ----------------
// grid: (S/64, H, B), 256 threads. Wave w owns q rows [q0+16w, q0+16w+16).
// Double-buffered K/V, single barrier per kv-tile, swizzled LDS.
__global__ __launch_bounds__(256) void attn(
    const bf16* __restrict__ Q, const bf16* __restrict__ K,
    const bf16* __restrict__ V, bf16* __restrict__ Y) {
  constexpr int S = 4096, D = 768;
  const int bq = gridDim.x - 1 - blockIdx.x;  // longest blocks dispatch first
  const int h = blockIdx.y;
  const int bb = blockIdx.z;
  const int tid = threadIdx.x, wave = tid >> 6, lane = tid & 63;
  const int lr = lane & 15, lg = lane >> 4;
  const int q0 = bq * 64;

  __shared__ alignas(16) bf16 Ks[2][2][64][32];   // [buf][ks][krow][kk] (swizzled)
  __shared__ alignas(16) bf16 Vt[2][2][64][32];   // [buf][ks][d][kk] = V^T (swizzled)
  __shared__ alignas(16) bf16 Ps[4][2][16][32];   // [wave][ks][qrow][kk] (swizzled)

  const size_t head = (size_t)bb * S * D + (size_t)h * 64;

  const int qrow = q0 + wave * 16 + lr;
  bf16x8 qf[2];
  qf[0] = *reinterpret_cast<const bf16x8*>(&Q[head + (size_t)qrow * D + lg * 8]);
  qf[1] = *reinterpret_cast<const bf16x8*>(&Q[head + (size_t)qrow * D + 32 + lg * 8]);

  f32x4 oacc[4] = {};
  float mrun[4], lrun[4];
#pragma unroll
  for (int i = 0; i < 4; ++i) { mrun[i] = -1e30f; lrun[i] = 0.f; }
  const float scale = 0.125f;

  auto stageK = [&](int kt, int buf) {
#pragma unroll
    for (int j = 0; j < 2; ++j) {
      int cb = (j * 4 + wave) * 64;  // wave-uniform chunk base within this buf
      int c = cb + lane;
      int s = c >> 8, r = (c >> 2) & 63, x = c & 3;
      int xs = (x ^ swzkey(r)) & 3;  // pre-swizzled source
      gload_lds16(&K[head + (size_t)(kt * 64 + r) * D + s * 32 + xs * 8],
                  &Ks[buf][0][0][0] + cb * 8);
    }
  };
  auto loadV = [&](int kt, bf16x8* vv) {
#pragma unroll
    for (int j = 0; j < 2; ++j) {
      int c = tid * 2 + j;  // 0..511
      int r = c >> 3, x = c & 7;
      vv[j] = *reinterpret_cast<const bf16x8*>(&V[head + (size_t)(kt * 64 + r) * D + x * 8]);
    }
  };
  auto writeV = [&](const bf16x8* vv, int buf) {
#pragma unroll
    for (int j = 0; j < 2; ++j) {
      int c = tid * 2 + j;
      int r = c >> 3, x = c & 7;
      int s = r >> 5, kk = r & 31;
      bf16* pl = &Vt[buf][s][0][0];
#pragma unroll
      for (int e = 0; e < 8; ++e) pl[swz32(x * 8 + e, kk)] = vv[j][e];
    }
  };

  // prologue: stage tile 0
  {
    stageK(0, 0);
    bf16x8 v0[2];
    loadV(0, v0);
    writeV(v0, 0);
  }
  __syncthreads();

  int cur = 0;
  for (int kt = 0; kt <= bq; ++kt) {
    const int kv0 = kt * 64;
    bf16x8 vnext[2];
    const bool more = (kt < bq);
    if (more) {
      stageK(kt + 1, cur ^ 1);   // K(t+1) in flight during compute(t)
      loadV(kt + 1, vnext);      // V(t+1) -> regs, in flight during compute(t)
    }

    // S = Q K^T
    f32x4 sacc[4] = {};
    __builtin_amdgcn_s_setprio(1);
#pragma unroll
    for (int n = 0; n < 4; ++n)
#pragma unroll
      for (int ks = 0; ks < 2; ++ks) {
        bf16x8 kf = *reinterpret_cast<const bf16x8*>(&Ks[cur][ks][0][0] + swz32(n * 16 + lr, lg * 8));
        sacc[n] = MFMA16(qf[ks], kf, sacc[n]);
      }
    __builtin_amdgcn_s_setprio(0);

    // scale (+ causal mask on the diagonal tile only)
    float sv[4][4];
    if (kt == bq) {
#pragma unroll
      for (int n = 0; n < 4; ++n) {
        int col = kv0 + n * 16 + lr;
#pragma unroll
        for (int i = 0; i < 4; ++i) {
          int row = q0 + wave * 16 + lg * 4 + i;
          sv[n][i] = (col > row) ? -1e30f : sacc[n][i] * scale;
        }
      }
    } else {
#pragma unroll
      for (int n = 0; n < 4; ++n)
#pragma unroll
        for (int i = 0; i < 4; ++i) sv[n][i] = sacc[n][i] * scale;
    }

    // online softmax (row stats live in the 16-lane group, per reg i)
    float alpha[4], tsum[4];
#pragma unroll
    for (int i = 0; i < 4; ++i) {
      float mx = fmaxf(fmaxf(sv[0][i], sv[1][i]), fmaxf(sv[2][i], sv[3][i]));
      mx = fmaxf(mx, __shfl_xor(mx, 1));
      mx = fmaxf(mx, __shfl_xor(mx, 2));
      mx = fmaxf(mx, __shfl_xor(mx, 4));
      mx = fmaxf(mx, __shfl_xor(mx, 8));
      float mnew = fmaxf(mrun[i], mx);
      alpha[i] = __expf(mrun[i] - mnew);
      mrun[i] = mnew;
      tsum[i] = 0.f;
    }
#pragma unroll
    for (int n = 0; n < 4; ++n)
#pragma unroll
      for (int i = 0; i < 4; ++i) {
        float p = __expf(sv[n][i] - mrun[i]);
        tsum[i] += p;
        (&Ps[wave][n >> 1][0][0])[swz32(lg * 4 + i, (n & 1) * 16 + lr)] = (bf16)p;
      }
#pragma unroll
    for (int i = 0; i < 4; ++i) {
      float su = tsum[i];
      su += __shfl_xor(su, 1);
      su += __shfl_xor(su, 2);
      su += __shfl_xor(su, 4);
      su += __shfl_xor(su, 8);
      lrun[i] = lrun[i] * alpha[i] + su;
    }
#pragma unroll
    for (int f = 0; f < 4; ++f)
#pragma unroll
      for (int i = 0; i < 4; ++i) oacc[f][i] *= alpha[i];

    // O += P V
    __builtin_amdgcn_s_setprio(1);
#pragma unroll
    for (int ks = 0; ks < 2; ++ks) {
      bf16x8 pf = *reinterpret_cast<const bf16x8*>(&Ps[wave][ks][0][0] + swz32(lr, lg * 8));
#pragma unroll
      for (int f = 0; f < 4; ++f) {
        bf16x8 vf = *reinterpret_cast<const bf16x8*>(&Vt[cur][ks][0][0] + swz32(f * 16 + lr, lg * 8));
        oacc[f] = MFMA16(pf, vf, oacc[f]);
      }
    }
    __builtin_amdgcn_s_setprio(0);

    if (more) {
      writeV(vnext, cur ^ 1);  // vmcnt drain happens here, after compute
      __syncthreads();         // compiler-emitted vmcnt(0) also covers K(t+1)
      cur ^= 1;
    }
  }

#pragma unroll
  for (int f = 0; f < 4; ++f)
#pragma unroll
    for (int i = 0; i < 4; ++i) {
      int row = q0 + wave * 16 + lg * 4 + i;
      float v = oacc[f][i] / lrun[i];
      Y[head + (size_t)row * D + f * 16 + lr] = (bf16)v;
    }
}

// ---------------- launcher ----------------
extern "C" void kernel_launch(void* const* d_in, const int* in_sizes, int n_in,
                              void* d_out, int out_size, void* d_ws, size_t ws_size,
                              hipStream_t stream) {
  const float* x  = (const float*)d_in[0];
  const float* Wq = (const float*)d_in[1];
  const float* bq = (const float*)d_in[2];
  const float* Wk = (const float*)d_in[3];
  const float* bk = (const float*)d_in[4];
  const float* Wv = (const float*)d_in[5];
  const float* bv = (const float*)d_in[6];
  const float* Wo = (const float*)d_in[7];
  const float* bo = (const float*)d_in[8];
  float* out = (float*)d_out;

  constexpr int Bx = 2, S = 4096, Dd = 768;
  constexpr int M = Bx * S;                   // 8192
  constexpr size_t XB = (size_t)M * Dd;       // 6291456 elems
  constexpr size_t WB = (size_t)Dd * Dd;      // 589824 elems

  char* ws = (char*)d_ws;
  bf16* xb = (bf16*)ws;                        // XB elems
  bf16* Wb = (bf16*)(ws + 2 * XB);             // 4*WB elems (Wq,Wk,Wv,Wo)
  bf16* Qb = (bf16*)(ws + 2 * XB + 8 * WB);    // XB
  bf16* Kb = Qb + XB;
  bf16* Vb = Kb + XB;
  bf16* Yb = Vb + XB;

  cvt_f32_bf16<<<2048, 256, 0, stream>>>(x, xb, (int)(XB / 4));
  cvt_f32_bf16<<<512, 256, 0, stream>>>(Wq, Wb + 0 * WB, (int)(WB / 4));
  cvt_f32_bf16<<<512, 256, 0, stream>>>(Wk, Wb + 1 * WB, (int)(WB / 4));
  cvt_f32_bf16<<<512, 256, 0, stream>>>(Wv, Wb + 2 * WB, (int)(WB / 4));
  cvt_f32_bf16<<<512, 256, 0, stream>>>(Wo, Wb + 3 * WB, (int)(WB / 4));

  // fused Q/K/V projections (z = 0,1,2), bf16 out
  gemm_bt<true><<<dim3(6, 64, 3), 256, 0, stream>>>(
      xb, Wb, bq, bk, bv, nullptr, Qb, M, Dd, Dd);

  // attention
  attn<<<dim3(S / 64, 12, Bx), 256, 0, stream>>>(Qb, Kb, Vb, Yb);

  // output projection, f32 out
  gemm_bt<false><<<dim3(6, 64, 1), 256, 0, stream>>>(
      Yb, Wb + 3 * WB, bo, bo, bo, out, nullptr, M, Dd, Dd);
}

// Round 3
// 253.937 us; speedup vs baseline: 1.7590x; 1.5774x over previous
//
#include <hip/hip_runtime.h>
#include <hip/hip_bf16.h>

typedef __bf16 bf16;
typedef __attribute__((ext_vector_type(8))) __bf16 bf16x8;
typedef __attribute__((ext_vector_type(4))) __bf16 bf16x4;
typedef __attribute__((ext_vector_type(4))) float f32x4;
typedef __attribute__((ext_vector_type(16))) float f32x16;

#define MFMA16(a, b, c) __builtin_amdgcn_mfma_f32_16x16x32_bf16((a), (b), (c), 0, 0, 0)
#define MFMA32(a, b, c) __builtin_amdgcn_mfma_f32_32x32x16_bf16((a), (b), (c), 0, 0, 0)

__device__ __forceinline__ void gload_lds16(const bf16* g, bf16* l) {
  __builtin_amdgcn_global_load_lds(
      (const __attribute__((address_space(1))) void*)g,
      (__attribute__((address_space(3))) void*)l, 16, 0, 0);
}

// swizzle helpers for [rows][32]-elem planes (GEMM tiles)
__device__ __forceinline__ int swz32(int row, int col) {
  int ch = ((col >> 3) ^ (row >> 1) ^ (row >> 3)) & 3;
  return row * 32 + ch * 8 + (col & 7);
}
__device__ __forceinline__ int swzkey(int row) { return ((row >> 1) ^ (row >> 3)) & 3; }

__device__ __forceinline__ unsigned pkbf(float a, float b) {
  union { unsigned u; bf16 h[2]; } w;
  w.h[0] = (bf16)a; w.h[1] = (bf16)b;
  return w.u;
}

// ---------------- f32 -> bf16 conversion ----------------
__global__ void cvt_f32_bf16(const float* __restrict__ in, bf16* __restrict__ out, int n4) {
  int stride = gridDim.x * blockDim.x;
  for (int i = blockIdx.x * blockDim.x + threadIdx.x; i < n4; i += stride) {
    float4 v = reinterpret_cast<const float4*>(in)[i];
    bf16x4 o = {(bf16)v.x, (bf16)v.y, (bf16)v.z, (bf16)v.w};
    reinterpret_cast<bf16x4*>(out)[i] = o;
  }
}

// ---------------- GEMM: C[M,N] = A[M,K] * W[N,K]^T + bias ----------------
template <bool OUT_BF16>
__global__ __launch_bounds__(256) void gemm_bt(
    const bf16* __restrict__ A, const bf16* __restrict__ W,
    const float* __restrict__ b0, const float* __restrict__ b1, const float* __restrict__ b2,
    float* __restrict__ Cf, bf16* __restrict__ Cb,
    int M, int N, int K) {
  const int z = blockIdx.z;
  const bf16* Wz = W + (size_t)z * N * K;
  const float* bias = (z == 0) ? b0 : (z == 1 ? b1 : b2);

  __shared__ alignas(16) bf16 As[128 * 32];
  __shared__ alignas(16) bf16 Bs[128 * 32];

  const int tid = threadIdx.x;
  const int wave = tid >> 6, lane = tid & 63;
  const int lr = lane & 15, lg = lane >> 4;
  const int wr = wave >> 1, wc = wave & 1;
  const int m0 = blockIdx.y * 128, n0 = blockIdx.x * 128;

  f32x4 acc[4][4] = {};

  for (int k0 = 0; k0 < K; k0 += 32) {
    __syncthreads();
#pragma unroll
    for (int j = 0; j < 2; ++j) {
      int cb = (j * 4 + wave) * 64;
      int c = cb + lane;
      int row = c >> 2, x = c & 3;
      int xs = (x ^ swzkey(row)) & 3;
      gload_lds16(&A[(size_t)(m0 + row) * K + k0 + xs * 8], &As[cb * 8]);
      gload_lds16(&Wz[(size_t)(n0 + row) * K + k0 + xs * 8], &Bs[cb * 8]);
    }
    __syncthreads();
    bf16x8 af[4], bfr[4];
#pragma unroll
    for (int m = 0; m < 4; ++m)
      af[m] = *reinterpret_cast<const bf16x8*>(&As[swz32(wr * 64 + m * 16 + lr, lg * 8)]);
#pragma unroll
    for (int n = 0; n < 4; ++n)
      bfr[n] = *reinterpret_cast<const bf16x8*>(&Bs[swz32(wc * 64 + n * 16 + lr, lg * 8)]);
    __builtin_amdgcn_s_setprio(1);
#pragma unroll
    for (int m = 0; m < 4; ++m)
#pragma unroll
      for (int n = 0; n < 4; ++n)
        acc[m][n] = MFMA16(af[m], bfr[n], acc[m][n]);
    __builtin_amdgcn_s_setprio(0);
  }

#pragma unroll
  for (int m = 0; m < 4; ++m) {
#pragma unroll
    for (int n = 0; n < 4; ++n) {
#pragma unroll
      for (int i = 0; i < 4; ++i) {
        int row = m0 + wr * 64 + m * 16 + lg * 4 + i;
        int col = n0 + wc * 64 + n * 16 + lr;
        float v = acc[m][n][i] + bias[col];
        if constexpr (OUT_BF16)
          (Cb + (size_t)z * M * N)[(size_t)row * N + col] = (bf16)v;
        else
          Cf[(size_t)row * N + col] = v;
      }
    }
  }
}

// ---------------- causal flash attention, 32x32 swapped-QK structure ----------------
// grid: (S/128, H, B), 4 waves. Wave w owns q rows [q0+32w, q0+32w+32).
// Lane (q=lane&31, hi=lane>>5) owns one q-row; S-values lane-local after swapped QK^T.
__global__ __launch_bounds__(256, 3) void attn32(
    const bf16* __restrict__ Q, const bf16* __restrict__ K,
    const bf16* __restrict__ V, bf16* __restrict__ Y) {
  constexpr int S = 4096, D = 768;
  const int qb = gridDim.x - 1 - blockIdx.x;  // longest blocks first
  const int h = blockIdx.y, bb = blockIdx.z;
  const int tid = threadIdx.x, wave = tid >> 6, lane = tid & 63;
  const int ln = lane & 31, hi = lane >> 5;
  const int q0 = qb * 128;
  const int qw0 = q0 + wave * 32;
  const int qrow = qw0 + ln;

  __shared__ alignas(16) bf16 Ks[2][64 * 64];  // [buf], row*64, chunk^=(row&7)
  __shared__ alignas(16) bf16 Vt[2][64 * 64];  // [buf] V^T, same swizzle

  const size_t head = (size_t)bb * S * D + (size_t)h * 64;
  const float SC2 = 0.125f * 1.44269504089f;  // scale * log2(e)

  // Q fragments in registers (B-operand: col=q, k=hi*8+j within 16-chunk c)
  bf16x8 qf[4];
  {
    const bf16* qp = Q + head + (size_t)qrow * D;
#pragma unroll
    for (int c = 0; c < 4; ++c)
      qf[c] = *reinterpret_cast<const bf16x8*>(qp + c * 16 + hi * 8);
  }

  f32x16 accO0 = {}, accO1 = {};
  float mrun = -1e4f, lrun = 0.f;

  auto stageK = [&](int t, int buf) {
#pragma unroll
    for (int j = 0; j < 2; ++j) {
      int c = (j * 4 + wave) * 64 + lane;  // chunk 0..511
      int r = c >> 3, ch = c & 7;
      int src = ((ch ^ (r & 7)) & 7) * 8;
      gload_lds16(&K[head + (size_t)(t * 64 + r) * D + src],
                  &Ks[buf][(j * 4 + wave) * 512]);
    }
  };
  auto loadV = [&](int t, bf16x8* vv) {
    int k0 = (tid & 31) * 2, d0 = (tid >> 5) * 8;
    vv[0] = *reinterpret_cast<const bf16x8*>(&V[head + (size_t)(t * 64 + k0) * D + d0]);
    vv[1] = *reinterpret_cast<const bf16x8*>(&V[head + (size_t)(t * 64 + k0 + 1) * D + d0]);
  };
  auto writeV = [&](const bf16x8* vv, int buf) {
    int k0 = (tid & 31) * 2, d0 = (tid >> 5) * 8;
#pragma unroll
    for (int e = 0; e < 8; ++e) {
      int row = d0 + e;
      int off = row * 64 + (((k0 >> 3) ^ (row & 7)) & 7) * 8 + (k0 & 7);
      unsigned w = pkbf(0.f, 0.f);
      union { unsigned u; bf16 h[2]; } pw;
      pw.h[0] = vv[0][e]; pw.h[1] = vv[1][e];
      *reinterpret_cast<unsigned*>(&Vt[buf][off]) = pw.u;
      (void)w;
    }
  };

  const int nt = q0 / 64 + 2;

  {
    stageK(0, 0);
    bf16x8 v0[2];
    loadV(0, v0);
    writeV(v0, 0);
  }
  __syncthreads();

  int cur = 0;
  for (int t = 0; t < nt; ++t) {
    const int kv0 = t * 64;
    const bool more = (t + 1 < nt);
    bf16x8 vnext[2];
    if (more) {
      stageK(t + 1, cur ^ 1);
      loadV(t + 1, vnext);
    }

    // ---- S^T = K Q^T : 8 MFMAs, lane holds 32 S-values for its q-row ----
    f32x16 s0 = {}, s1 = {};
    __builtin_amdgcn_s_setprio(1);
#pragma unroll
    for (int c = 0; c < 4; ++c) {
      int r0 = ln, r1 = 32 + ln;
      int ch0 = ((2 * c + hi) ^ (r0 & 7)) & 7;
      int ch1 = ((2 * c + hi) ^ (r1 & 7)) & 7;
      bf16x8 kf0 = *reinterpret_cast<const bf16x8*>(&Ks[cur][r0 * 64 + ch0 * 8]);
      bf16x8 kf1 = *reinterpret_cast<const bf16x8*>(&Ks[cur][r1 * 64 + ch1 * 8]);
      s0 = MFMA32(kf0, qf[c], s0);
      s1 = MFMA32(kf1, qf[c], s1);
    }
    __builtin_amdgcn_s_setprio(0);

    // ---- softmax (lane-local row) ----
    float sv[32];
#pragma unroll
    for (int r = 0; r < 16; ++r) {
      sv[r] = s0[r] * SC2;
      sv[16 + r] = s1[r] * SC2;
    }
    if (kv0 + 63 > qw0) {  // diagonal / masked region
#pragma unroll
      for (int r = 0; r < 16; ++r) {
        int kl = (r & 3) + 8 * (r >> 2) + 4 * hi;
        if (kv0 + kl > qrow) sv[r] = -1e30f;
        if (kv0 + 32 + kl > qrow) sv[16 + r] = -1e30f;
      }
    }
    float pm = sv[0];
#pragma unroll
    for (int r = 1; r < 32; ++r) pm = fmaxf(pm, sv[r]);
    pm = fmaxf(pm, __shfl_xor(pm, 32));
    float mnew = fmaxf(mrun, pm);
    float alpha = __builtin_amdgcn_exp2f(mrun - mnew);
    mrun = mnew;

    float p[32];
    float ts0 = 0.f, ts1 = 0.f, ts2 = 0.f, ts3 = 0.f;
#pragma unroll
    for (int r = 0; r < 32; r += 4) {
      p[r] = __builtin_amdgcn_exp2f(sv[r] - mnew);
      p[r + 1] = __builtin_amdgcn_exp2f(sv[r + 1] - mnew);
      p[r + 2] = __builtin_amdgcn_exp2f(sv[r + 2] - mnew);
      p[r + 3] = __builtin_amdgcn_exp2f(sv[r + 3] - mnew);
      ts0 += p[r]; ts1 += p[r + 1]; ts2 += p[r + 2]; ts3 += p[r + 3];
    }
    float ts = (ts0 + ts1) + (ts2 + ts3);
    ts += __shfl_xor(ts, 32);
    lrun = lrun * alpha + ts;

#pragma unroll
    for (int r = 0; r < 16; ++r) { accO0[r] *= alpha; accO1[r] *= alpha; }

    // ---- pack P to bf16 fragments in-register (4 shfl_xor per tile) ----
    __builtin_amdgcn_s_setprio(1);
#pragma unroll
    for (int kg = 0; kg < 2; ++kg) {
      const float* pv = &p[kg * 16];
      unsigned w0 = pkbf(pv[0], pv[1]), w1 = pkbf(pv[2], pv[3]);
      unsigned w2 = pkbf(pv[4], pv[5]), w3 = pkbf(pv[6], pv[7]);
      unsigned w4 = pkbf(pv[8], pv[9]), w5 = pkbf(pv[10], pv[11]);
      unsigned w6 = pkbf(pv[12], pv[13]), w7 = pkbf(pv[14], pv[15]);
      unsigned X0 = hi ? w0 : w2, X1 = hi ? w1 : w3;
      unsigned X2 = hi ? w4 : w6, X3 = hi ? w5 : w7;
      unsigned Y0 = __shfl_xor((int)X0, 32), Y1 = __shfl_xor((int)X1, 32);
      unsigned Y2 = __shfl_xor((int)X2, 32), Y3 = __shfl_xor((int)X3, 32);
      union { unsigned u[4]; bf16x8 v; } fe, fo;
      fe.u[0] = hi ? Y0 : w0; fe.u[1] = hi ? Y1 : w1;
      fe.u[2] = hi ? w2 : Y0; fe.u[3] = hi ? w3 : Y1;
      fo.u[0] = hi ? Y2 : w4; fo.u[1] = hi ? Y3 : w5;
      fo.u[2] = hi ? w6 : Y2; fo.u[3] = hi ? w7 : Y3;

      // PV: O^T += V^T * P^T for kc = 2kg, 2kg+1
#pragma unroll
      for (int half = 0; half < 2; ++half) {
        int kc = 2 * kg + half;
        bf16x8 pf = half ? fo.v : fe.v;
        int r0 = ln, r1 = 32 + ln;
        int ch0 = ((2 * kc + hi) ^ (r0 & 7)) & 7;
        int ch1 = ((2 * kc + hi) ^ (r1 & 7)) & 7;
        bf16x8 vf0 = *reinterpret_cast<const bf16x8*>(&Vt[cur][r0 * 64 + ch0 * 8]);
        bf16x8 vf1 = *reinterpret_cast<const bf16x8*>(&Vt[cur][r1 * 64 + ch1 * 8]);
        accO0 = MFMA32(vf0, pf, accO0);
        accO1 = MFMA32(vf1, pf, accO1);
      }
    }
    __builtin_amdgcn_s_setprio(0);

    if (more) {
      writeV(vnext, cur ^ 1);
      __syncthreads();
      cur ^= 1;
    }
  }

  // ---- epilogue: O[q][d] = accO/lrun, d = dg*32 + 8*(r>>2) + 4*hi + (r&3) ----
  float inv = 1.f / lrun;
  bf16* yp = Y + head + (size_t)qrow * D;
#pragma unroll
  for (int g = 0; g < 4; ++g) {
    bf16x4 o0, o1;
#pragma unroll
    for (int i = 0; i < 4; ++i) {
      o0[i] = (bf16)(accO0[g * 4 + i] * inv);
      o1[i] = (bf16)(accO1[g * 4 + i] * inv);
    }
    *reinterpret_cast<bf16x4*>(yp + 8 * g + 4 * hi) = o0;
    *reinterpret_cast<bf16x4*>(yp + 32 + 8 * g + 4 * hi) = o1;
  }
}

// ---------------- launcher ----------------
extern "C" void kernel_launch(void* const* d_in, const int* in_sizes, int n_in,
                              void* d_out, int out_size, void* d_ws, size_t ws_size,
                              hipStream_t stream) {
  const float* x  = (const float*)d_in[0];
  const float* Wq = (const float*)d_in[1];
  const float* bq = (const float*)d_in[2];
  const float* Wk = (const float*)d_in[3];
  const float* bk = (const float*)d_in[4];
  const float* Wv = (const float*)d_in[5];
  const float* bv = (const float*)d_in[6];
  const float* Wo = (const float*)d_in[7];
  const float* bo = (const float*)d_in[8];
  float* out = (float*)d_out;

  constexpr int Bx = 2, S = 4096, Dd = 768;
  constexpr int M = Bx * S;                   // 8192
  constexpr size_t XB = (size_t)M * Dd;       // 6291456 elems
  constexpr size_t WB = (size_t)Dd * Dd;      // 589824 elems

  char* ws = (char*)d_ws;
  bf16* xb = (bf16*)ws;                        // XB elems
  bf16* Wb = (bf16*)(ws + 2 * XB);             // 4*WB elems (Wq,Wk,Wv,Wo)
  bf16* Qb = (bf16*)(ws + 2 * XB + 8 * WB);    // XB
  bf16* Kb = Qb + XB;
  bf16* Vb = Kb + XB;
  bf16* Yb = Vb + XB;

  cvt_f32_bf16<<<2048, 256, 0, stream>>>(x, xb, (int)(XB / 4));
  cvt_f32_bf16<<<512, 256, 0, stream>>>(Wq, Wb + 0 * WB, (int)(WB / 4));
  cvt_f32_bf16<<<512, 256, 0, stream>>>(Wk, Wb + 1 * WB, (int)(WB / 4));
  cvt_f32_bf16<<<512, 256, 0, stream>>>(Wv, Wb + 2 * WB, (int)(WB / 4));
  cvt_f32_bf16<<<512, 256, 0, stream>>>(Wo, Wb + 3 * WB, (int)(WB / 4));

  // fused Q/K/V projections (z = 0,1,2), bf16 out
  gemm_bt<true><<<dim3(6, 64, 3), 256, 0, stream>>>(
      xb, Wb, bq, bk, bv, nullptr, Qb, M, Dd, Dd);

  // attention (32x32 swapped structure)
  attn32<<<dim3(S / 128, 12, Bx), 256, 0, stream>>>(Qb, Kb, Vb, Yb);

  // output projection, f32 out
  gemm_bt<false><<<dim3(6, 64, 1), 256, 0, stream>>>(
      Yb, Wb + 3 * WB, bo, bo, bo, out, nullptr, M, Dd, Dd);
}

// Round 4
// 252.250 us; speedup vs baseline: 1.7707x; 1.0067x over previous
//
#include <hip/hip_runtime.h>
#include <hip/hip_bf16.h>

typedef __bf16 bf16;
typedef __attribute__((ext_vector_type(8))) __bf16 bf16x8;
typedef __attribute__((ext_vector_type(4))) __bf16 bf16x4;
typedef __attribute__((ext_vector_type(4))) float f32x4;
typedef __attribute__((ext_vector_type(16))) float f32x16;

#define MFMA16(a, b, c) __builtin_amdgcn_mfma_f32_16x16x32_bf16((a), (b), (c), 0, 0, 0)
#define MFMA32(a, b, c) __builtin_amdgcn_mfma_f32_32x32x16_bf16((a), (b), (c), 0, 0, 0)

__device__ __forceinline__ void gload_lds16(const bf16* g, bf16* l) {
  __builtin_amdgcn_global_load_lds(
      (const __attribute__((address_space(1))) void*)g,
      (__attribute__((address_space(3))) void*)l, 16, 0, 0);
}

// swizzle helpers for [rows][32]-elem planes (GEMM tiles)
__device__ __forceinline__ int swz32(int row, int col) {
  int ch = ((col >> 3) ^ (row >> 1) ^ (row >> 3)) & 3;
  return row * 32 + ch * 8 + (col & 7);
}
__device__ __forceinline__ int swzkey(int row) { return ((row >> 1) ^ (row >> 3)) & 3; }

__device__ __forceinline__ unsigned pkbf(float a, float b) {
  union { unsigned u; bf16 h[2]; } w;
  w.h[0] = (bf16)a; w.h[1] = (bf16)b;
  return w.u;
}

// ---------------- fused f32 -> bf16 conversion (x + 4 weights, 1 dispatch) ----------------
__global__ void cvt_all(const float* __restrict__ x,
                        const float* __restrict__ wq, const float* __restrict__ wk,
                        const float* __restrict__ wv, const float* __restrict__ wo,
                        bf16* __restrict__ xb, bf16* __restrict__ Wb) {
  constexpr int NX4 = 6291456 / 4;   // x
  constexpr int NW4 = 589824 / 4;    // one weight
  constexpr int TOT = NX4 + 4 * NW4;
  int stride = gridDim.x * blockDim.x;
  for (int i = blockIdx.x * blockDim.x + threadIdx.x; i < TOT; i += stride) {
    const float4* src;
    bf16x4* dst;
    if (i < NX4) {
      src = reinterpret_cast<const float4*>(x) + i;
      dst = reinterpret_cast<bf16x4*>(xb) + i;
    } else {
      int j = i - NX4;
      int w = j / NW4, r = j - w * NW4;
      const float* sp = (w == 0) ? wq : (w == 1) ? wk : (w == 2) ? wv : wo;
      src = reinterpret_cast<const float4*>(sp) + r;
      dst = reinterpret_cast<bf16x4*>(Wb) + j;
    }
    float4 v = *src;
    bf16x4 o = {(bf16)v.x, (bf16)v.y, (bf16)v.z, (bf16)v.w};
    *dst = o;
  }
}

// ---------------- GEMM: C[M,N] = A[M,K] * W[N,K]^T + bias ----------------
template <bool OUT_BF16>
__global__ __launch_bounds__(256) void gemm_bt(
    const bf16* __restrict__ A, const bf16* __restrict__ W,
    const float* __restrict__ b0, const float* __restrict__ b1, const float* __restrict__ b2,
    float* __restrict__ Cf, bf16* __restrict__ Cb,
    int M, int N, int K) {
  const int z = blockIdx.z;
  const bf16* Wz = W + (size_t)z * N * K;
  const float* bias = (z == 0) ? b0 : (z == 1 ? b1 : b2);

  __shared__ alignas(16) bf16 As[128 * 32];
  __shared__ alignas(16) bf16 Bs[128 * 32];

  const int tid = threadIdx.x;
  const int wave = tid >> 6, lane = tid & 63;
  const int lr = lane & 15, lg = lane >> 4;
  const int wr = wave >> 1, wc = wave & 1;
  const int m0 = blockIdx.y * 128, n0 = blockIdx.x * 128;

  f32x4 acc[4][4] = {};

  for (int k0 = 0; k0 < K; k0 += 32) {
    __syncthreads();
#pragma unroll
    for (int j = 0; j < 2; ++j) {
      int cb = (j * 4 + wave) * 64;
      int c = cb + lane;
      int row = c >> 2, x = c & 3;
      int xs = (x ^ swzkey(row)) & 3;
      gload_lds16(&A[(size_t)(m0 + row) * K + k0 + xs * 8], &As[cb * 8]);
      gload_lds16(&Wz[(size_t)(n0 + row) * K + k0 + xs * 8], &Bs[cb * 8]);
    }
    __syncthreads();
    bf16x8 af[4], bfr[4];
#pragma unroll
    for (int m = 0; m < 4; ++m)
      af[m] = *reinterpret_cast<const bf16x8*>(&As[swz32(wr * 64 + m * 16 + lr, lg * 8)]);
#pragma unroll
    for (int n = 0; n < 4; ++n)
      bfr[n] = *reinterpret_cast<const bf16x8*>(&Bs[swz32(wc * 64 + n * 16 + lr, lg * 8)]);
    __builtin_amdgcn_s_setprio(1);
#pragma unroll
    for (int m = 0; m < 4; ++m)
#pragma unroll
      for (int n = 0; n < 4; ++n)
        acc[m][n] = MFMA16(af[m], bfr[n], acc[m][n]);
    __builtin_amdgcn_s_setprio(0);
  }

#pragma unroll
  for (int m = 0; m < 4; ++m) {
#pragma unroll
    for (int n = 0; n < 4; ++n) {
#pragma unroll
      for (int i = 0; i < 4; ++i) {
        int row = m0 + wr * 64 + m * 16 + lg * 4 + i;
        int col = n0 + wc * 64 + n * 16 + lr;
        float v = acc[m][n][i] + bias[col];
        if constexpr (OUT_BF16)
          (Cb + (size_t)z * M * N)[(size_t)row * N + col] = (bf16)v;
        else
          Cf[(size_t)row * N + col] = v;
      }
    }
  }
}

// ---------------- causal flash attention, 32x32 swapped-QK structure ----------------
__global__ __launch_bounds__(256, 3) void attn32(
    const bf16* __restrict__ Q, const bf16* __restrict__ K,
    const bf16* __restrict__ V, bf16* __restrict__ Y) {
  constexpr int S = 4096, D = 768;
  const int qb = gridDim.x - 1 - blockIdx.x;  // longest blocks first
  const int h = blockIdx.y, bb = blockIdx.z;
  const int tid = threadIdx.x, wave = tid >> 6, lane = tid & 63;
  const int ln = lane & 31, hi = lane >> 5;
  const int q0 = qb * 128;
  const int qw0 = q0 + wave * 32;
  const int qrow = qw0 + ln;

  __shared__ alignas(16) bf16 Ks[2][64 * 64];  // [buf], row*64, chunk^=(row&7)
  __shared__ alignas(16) bf16 Vt[2][64 * 64];  // [buf] V^T, same swizzle

  const size_t head = (size_t)bb * S * D + (size_t)h * 64;
  const float SC2 = 0.125f * 1.44269504089f;  // scale * log2(e), folded into Q

  // Q fragments in registers, pre-scaled by SC2 (exp2 domain)
  bf16x8 qf[4];
  {
    const bf16* qp = Q + head + (size_t)qrow * D;
#pragma unroll
    for (int c = 0; c < 4; ++c) {
      bf16x8 t = *reinterpret_cast<const bf16x8*>(qp + c * 16 + hi * 8);
#pragma unroll
      for (int e = 0; e < 8; ++e) t[e] = (bf16)((float)t[e] * SC2);
      qf[c] = t;
    }
  }

  f32x16 accO0 = {}, accO1 = {};
  float mrun = -1e4f, lrun = 0.f;

  auto stageK = [&](int t, int buf) {
#pragma unroll
    for (int j = 0; j < 2; ++j) {
      int c = (j * 4 + wave) * 64 + lane;  // chunk 0..511
      int r = c >> 3, ch = c & 7;
      int src = ((ch ^ (r & 7)) & 7) * 8;
      gload_lds16(&K[head + (size_t)(t * 64 + r) * D + src],
                  &Ks[buf][(j * 4 + wave) * 512]);
    }
  };
  auto loadV = [&](int t, bf16x8* vv) {
    int k0 = (tid & 31) * 2, d0 = (tid >> 5) * 8;
    vv[0] = *reinterpret_cast<const bf16x8*>(&V[head + (size_t)(t * 64 + k0) * D + d0]);
    vv[1] = *reinterpret_cast<const bf16x8*>(&V[head + (size_t)(t * 64 + k0 + 1) * D + d0]);
  };
  auto writeV = [&](const bf16x8* vv, int buf) {
    int k0 = (tid & 31) * 2, d0 = (tid >> 5) * 8;
#pragma unroll
    for (int e = 0; e < 8; ++e) {
      int row = d0 + e;
      int off = row * 64 + (((k0 >> 3) ^ (row & 7)) & 7) * 8 + (k0 & 7);
      union { unsigned u; bf16 h[2]; } pw;
      pw.h[0] = vv[0][e]; pw.h[1] = vv[1][e];
      *reinterpret_cast<unsigned*>(&Vt[buf][off]) = pw.u;
    }
  };

  const int nt = q0 / 64 + 2;

  {
    stageK(0, 0);
    bf16x8 v0[2];
    loadV(0, v0);
    writeV(v0, 0);
  }
  __syncthreads();

  int cur = 0;
  for (int t = 0; t < nt; ++t) {
    const int kv0 = t * 64;
    const bool more = (t + 1 < nt);
    bf16x8 vnext[2];
    if (more) {
      stageK(t + 1, cur ^ 1);
      loadV(t + 1, vnext);
    }

    // fully-masked tile for this wave: contributes exactly zero -> skip compute
    if (kv0 <= qw0 + 31) {
      // ---- S^T = K Q^T : 8 MFMAs, lane holds 32 S-values (exp2 domain) ----
      f32x16 s0 = {}, s1 = {};
      __builtin_amdgcn_s_setprio(1);
#pragma unroll
      for (int c = 0; c < 4; ++c) {
        int r0 = ln, r1 = 32 + ln;
        int ch0 = ((2 * c + hi) ^ (r0 & 7)) & 7;
        int ch1 = ((2 * c + hi) ^ (r1 & 7)) & 7;
        bf16x8 kf0 = *reinterpret_cast<const bf16x8*>(&Ks[cur][r0 * 64 + ch0 * 8]);
        bf16x8 kf1 = *reinterpret_cast<const bf16x8*>(&Ks[cur][r1 * 64 + ch1 * 8]);
        s0 = MFMA32(kf0, qf[c], s0);
        s1 = MFMA32(kf1, qf[c], s1);
      }
      __builtin_amdgcn_s_setprio(0);

      float sv[32];
#pragma unroll
      for (int r = 0; r < 16; ++r) { sv[r] = s0[r]; sv[16 + r] = s1[r]; }
      if (kv0 + 63 > qw0) {  // diagonal / masked region
#pragma unroll
        for (int r = 0; r < 16; ++r) {
          int kl = (r & 3) + 8 * (r >> 2) + 4 * hi;
          if (kv0 + kl > qrow) sv[r] = -1e30f;
          if (kv0 + 32 + kl > qrow) sv[16 + r] = -1e30f;
        }
      }

      // tree max (depth 5, max3-fusable)
      float t16[16];
#pragma unroll
      for (int r = 0; r < 16; ++r) t16[r] = fmaxf(sv[r], sv[r + 16]);
#pragma unroll
      for (int r = 0; r < 8; ++r) t16[r] = fmaxf(t16[r], t16[r + 8]);
#pragma unroll
      for (int r = 0; r < 4; ++r) t16[r] = fmaxf(t16[r], t16[r + 4]);
      float pm = fmaxf(fmaxf(t16[0], t16[1]), fmaxf(t16[2], t16[3]));

      // defer-max (T13): only rescale when the max actually grew past THR=8
      if (!__all(pm - mrun <= 8.0f)) {
        pm = fmaxf(pm, __shfl_xor(pm, 32));
        float mnew = fmaxf(mrun, pm);
        float alpha = __builtin_amdgcn_exp2f(mrun - mnew);
        mrun = mnew;
        lrun *= alpha;
#pragma unroll
        for (int r = 0; r < 16; ++r) { accO0[r] *= alpha; accO1[r] *= alpha; }
      }

      float p[32];
      float ts0 = 0.f, ts1 = 0.f, ts2 = 0.f, ts3 = 0.f;
#pragma unroll
      for (int r = 0; r < 32; r += 4) {
        p[r] = __builtin_amdgcn_exp2f(sv[r] - mrun);
        p[r + 1] = __builtin_amdgcn_exp2f(sv[r + 1] - mrun);
        p[r + 2] = __builtin_amdgcn_exp2f(sv[r + 2] - mrun);
        p[r + 3] = __builtin_amdgcn_exp2f(sv[r + 3] - mrun);
        ts0 += p[r]; ts1 += p[r + 1]; ts2 += p[r + 2]; ts3 += p[r + 3];
      }
      float ts = (ts0 + ts1) + (ts2 + ts3);
      ts += __shfl_xor(ts, 32);
      lrun += ts;

      // ---- pack P to bf16 fragments in-register; PV ----
      __builtin_amdgcn_s_setprio(1);
#pragma unroll
      for (int kg = 0; kg < 2; ++kg) {
        const float* pv = &p[kg * 16];
        unsigned w0 = pkbf(pv[0], pv[1]), w1 = pkbf(pv[2], pv[3]);
        unsigned w2 = pkbf(pv[4], pv[5]), w3 = pkbf(pv[6], pv[7]);
        unsigned w4 = pkbf(pv[8], pv[9]), w5 = pkbf(pv[10], pv[11]);
        unsigned w6 = pkbf(pv[12], pv[13]), w7 = pkbf(pv[14], pv[15]);
        unsigned X0 = hi ? w0 : w2, X1 = hi ? w1 : w3;
        unsigned X2 = hi ? w4 : w6, X3 = hi ? w5 : w7;
        unsigned Y0 = __shfl_xor((int)X0, 32), Y1 = __shfl_xor((int)X1, 32);
        unsigned Y2 = __shfl_xor((int)X2, 32), Y3 = __shfl_xor((int)X3, 32);
        union { unsigned u[4]; bf16x8 v; } fe, fo;
        fe.u[0] = hi ? Y0 : w0; fe.u[1] = hi ? Y1 : w1;
        fe.u[2] = hi ? w2 : Y0; fe.u[3] = hi ? w3 : Y1;
        fo.u[0] = hi ? Y2 : w4; fo.u[1] = hi ? Y3 : w5;
        fo.u[2] = hi ? w6 : Y2; fo.u[3] = hi ? w7 : Y3;

#pragma unroll
        for (int half = 0; half < 2; ++half) {
          int kc = 2 * kg + half;
          bf16x8 pf = half ? fo.v : fe.v;
          int r0 = ln, r1 = 32 + ln;
          int ch0 = ((2 * kc + hi) ^ (r0 & 7)) & 7;
          int ch1 = ((2 * kc + hi) ^ (r1 & 7)) & 7;
          bf16x8 vf0 = *reinterpret_cast<const bf16x8*>(&Vt[cur][r0 * 64 + ch0 * 8]);
          bf16x8 vf1 = *reinterpret_cast<const bf16x8*>(&Vt[cur][r1 * 64 + ch1 * 8]);
          accO0 = MFMA32(vf0, pf, accO0);
          accO1 = MFMA32(vf1, pf, accO1);
        }
      }
      __builtin_amdgcn_s_setprio(0);
    }

    if (more) {
      writeV(vnext, cur ^ 1);
      __syncthreads();
      cur ^= 1;
    }
  }

  // ---- epilogue ----
  float inv = 1.f / lrun;
  bf16* yp = Y + head + (size_t)qrow * D;
#pragma unroll
  for (int g = 0; g < 4; ++g) {
    bf16x4 o0, o1;
#pragma unroll
    for (int i = 0; i < 4; ++i) {
      o0[i] = (bf16)(accO0[g * 4 + i] * inv);
      o1[i] = (bf16)(accO1[g * 4 + i] * inv);
    }
    *reinterpret_cast<bf16x4*>(yp + 8 * g + 4 * hi) = o0;
    *reinterpret_cast<bf16x4*>(yp + 32 + 8 * g + 4 * hi) = o1;
  }
}

// ---------------- launcher ----------------
extern "C" void kernel_launch(void* const* d_in, const int* in_sizes, int n_in,
                              void* d_out, int out_size, void* d_ws, size_t ws_size,
                              hipStream_t stream) {
  const float* x  = (const float*)d_in[0];
  const float* Wq = (const float*)d_in[1];
  const float* bq = (const float*)d_in[2];
  const float* Wk = (const float*)d_in[3];
  const float* bk = (const float*)d_in[4];
  const float* Wv = (const float*)d_in[5];
  const float* bv = (const float*)d_in[6];
  const float* Wo = (const float*)d_in[7];
  const float* bo = (const float*)d_in[8];
  float* out = (float*)d_out;

  constexpr int Bx = 2, S = 4096, Dd = 768;
  constexpr int M = Bx * S;                   // 8192
  constexpr size_t XB = (size_t)M * Dd;       // 6291456 elems
  constexpr size_t WB = (size_t)Dd * Dd;      // 589824 elems

  char* ws = (char*)d_ws;
  bf16* xb = (bf16*)ws;                        // XB elems
  bf16* Wb = (bf16*)(ws + 2 * XB);             // 4*WB elems (Wq,Wk,Wv,Wo)
  bf16* Qb = (bf16*)(ws + 2 * XB + 8 * WB);    // XB
  bf16* Kb = Qb + XB;
  bf16* Vb = Kb + XB;
  bf16* Yb = Vb + XB;

  cvt_all<<<2048, 256, 0, stream>>>(x, Wq, Wk, Wv, Wo, xb, Wb);

  // fused Q/K/V projections (z = 0,1,2), bf16 out
  gemm_bt<true><<<dim3(6, 64, 3), 256, 0, stream>>>(
      xb, Wb, bq, bk, bv, nullptr, Qb, M, Dd, Dd);

  // attention (32x32 swapped structure)
  attn32<<<dim3(S / 128, 12, Bx), 256, 0, stream>>>(Qb, Kb, Vb, Yb);

  // output projection, f32 out
  gemm_bt<false><<<dim3(6, 64, 1), 256, 0, stream>>>(
      Yb, Wb + 3 * WB, bo, bo, bo, out, nullptr, M, Dd, Dd);
}

// Round 5
// 215.462 us; speedup vs baseline: 2.0731x; 1.1707x over previous
//
#include <hip/hip_runtime.h>
#include <hip/hip_bf16.h>

typedef __bf16 bf16;
typedef __attribute__((ext_vector_type(8))) __bf16 bf16x8;
typedef __attribute__((ext_vector_type(4))) __bf16 bf16x4;
typedef __attribute__((ext_vector_type(4))) float f32x4;
typedef __attribute__((ext_vector_type(16))) float f32x16;

#if __has_builtin(__builtin_amdgcn_permlane32_swap)
#define HAVE_PLSWAP 1
typedef __attribute__((ext_vector_type(2))) unsigned uint2v;
#endif

#define MFMA16(a, b, c) __builtin_amdgcn_mfma_f32_16x16x32_bf16((a), (b), (c), 0, 0, 0)
#define MFMA32(a, b, c) __builtin_amdgcn_mfma_f32_32x32x16_bf16((a), (b), (c), 0, 0, 0)

__device__ __forceinline__ void gload_lds16(const bf16* g, bf16* l) {
  __builtin_amdgcn_global_load_lds(
      (const __attribute__((address_space(1))) void*)g,
      (__attribute__((address_space(3))) void*)l, 16, 0, 0);
}

__device__ __forceinline__ unsigned pkbf(float a, float b) {
  union { unsigned u; bf16 h[2]; } w;
  w.h[0] = (bf16)a; w.h[1] = (bf16)b;
  return w.u;
}

__device__ __forceinline__ float mx3(float a, float b, float c) {
  return fmaxf(fmaxf(a, b), c);
}

// ---------------- fused f32 -> bf16 conversion (x + 4 weights, 1 dispatch) ----------------
__global__ void cvt_all(const float* __restrict__ x,
                        const float* __restrict__ wq, const float* __restrict__ wk,
                        const float* __restrict__ wv, const float* __restrict__ wo,
                        bf16* __restrict__ xb, bf16* __restrict__ Wb) {
  constexpr int NX4 = 6291456 / 4;
  constexpr int NW4 = 589824 / 4;
  constexpr int TOT = NX4 + 4 * NW4;
  int stride = gridDim.x * blockDim.x;
  for (int i = blockIdx.x * blockDim.x + threadIdx.x; i < TOT; i += stride) {
    const float4* src;
    bf16x4* dst;
    if (i < NX4) {
      src = reinterpret_cast<const float4*>(x) + i;
      dst = reinterpret_cast<bf16x4*>(xb) + i;
    } else {
      int j = i - NX4;
      int w = j / NW4, r = j - w * NW4;
      const float* sp = (w == 0) ? wq : (w == 1) ? wk : (w == 2) ? wv : wo;
      src = reinterpret_cast<const float4*>(sp) + r;
      dst = reinterpret_cast<bf16x4*>(Wb) + j;
    }
    float4 v = *src;
    bf16x4 o = {(bf16)v.x, (bf16)v.y, (bf16)v.z, (bf16)v.w};
    *dst = o;
  }
}

// ---------------- GEMM: C[M,N] = A[M,K] * W[N,K]^T + bias, BK=64 ----------------
template <bool OUT_BF16>
__global__ __launch_bounds__(256) void gemm_bt(
    const bf16* __restrict__ A, const bf16* __restrict__ W,
    const float* __restrict__ b0, const float* __restrict__ b1, const float* __restrict__ b2,
    float* __restrict__ Cf, bf16* __restrict__ Cb,
    int M, int N, int K) {
  const int z = blockIdx.z;
  const bf16* Wz = W + (size_t)z * N * K;
  const float* bias = (z == 0) ? b0 : (z == 1 ? b1 : b2);

  __shared__ alignas(16) bf16 As[128 * 64];
  __shared__ alignas(16) bf16 Bs[128 * 64];

  const int tid = threadIdx.x;
  const int wave = tid >> 6, lane = tid & 63;
  const int lr = lane & 15, lg = lane >> 4;
  const int wr = wave >> 1, wc = wave & 1;
  const int m0 = blockIdx.y * 128, n0 = blockIdx.x * 128;

  f32x4 acc[4][4] = {};

  for (int k0 = 0; k0 < K; k0 += 64) {
    __syncthreads();
#pragma unroll
    for (int j = 0; j < 4; ++j) {
      int cb = j * 256 + wave * 64;  // wave-uniform chunk base
      int c = cb + lane;
      int row = c >> 3, x = c & 7;
      int xs = x ^ (row & 7);  // pre-swizzled source (3-bit XOR)
      gload_lds16(&A[(size_t)(m0 + row) * K + k0 + xs * 8], &As[cb * 8]);
      gload_lds16(&Wz[(size_t)(n0 + row) * K + k0 + xs * 8], &Bs[cb * 8]);
    }
    __syncthreads();
#pragma unroll
    for (int kk = 0; kk < 2; ++kk) {
      bf16x8 af[4], bfr[4];
#pragma unroll
      for (int m = 0; m < 4; ++m) {
        int row = wr * 64 + m * 16 + lr;
        int ch = (kk * 4 + lg) ^ (row & 7);
        af[m] = *reinterpret_cast<const bf16x8*>(&As[row * 64 + ch * 8]);
      }
#pragma unroll
      for (int n = 0; n < 4; ++n) {
        int row = wc * 64 + n * 16 + lr;
        int ch = (kk * 4 + lg) ^ (row & 7);
        bfr[n] = *reinterpret_cast<const bf16x8*>(&Bs[row * 64 + ch * 8]);
      }
      __builtin_amdgcn_s_setprio(1);
#pragma unroll
      for (int m = 0; m < 4; ++m)
#pragma unroll
        for (int n = 0; n < 4; ++n)
          acc[m][n] = MFMA16(af[m], bfr[n], acc[m][n]);
      __builtin_amdgcn_s_setprio(0);
    }
  }

#pragma unroll
  for (int m = 0; m < 4; ++m) {
#pragma unroll
    for (int n = 0; n < 4; ++n) {
#pragma unroll
      for (int i = 0; i < 4; ++i) {
        int row = m0 + wr * 64 + m * 16 + lg * 4 + i;
        int col = n0 + wc * 64 + n * 16 + lr;
        float v = acc[m][n][i] + bias[col];
        if constexpr (OUT_BF16)
          (Cb + (size_t)z * M * N)[(size_t)row * N + col] = (bf16)v;
        else
          Cf[(size_t)row * N + col] = v;
      }
    }
  }
}

// ---------------- causal flash attention, 32x32 swapped-QK structure ----------------
__global__ __launch_bounds__(256, 3) void attn32(
    const bf16* __restrict__ Q, const bf16* __restrict__ K,
    const bf16* __restrict__ V, bf16* __restrict__ Y) {
  constexpr int S = 4096, D = 768;
  const int qb = gridDim.x - 1 - blockIdx.x;  // longest blocks first
  const int h = blockIdx.y, bb = blockIdx.z;
  const int tid = threadIdx.x, wave = tid >> 6, lane = tid & 63;
  const int ln = lane & 31, hi = lane >> 5;
  const int q0 = qb * 128;
  const int qw0 = q0 + wave * 32;
  const int qrow = qw0 + ln;

  __shared__ alignas(16) bf16 Ks[2][64 * 64];  // [buf], row*64, chunk^=(row&7)
  __shared__ alignas(16) bf16 Vt[2][64 * 64];  // [buf] V^T, same swizzle

  const size_t head = (size_t)bb * S * D + (size_t)h * 64;
  const float SC2 = 0.125f * 1.44269504089f;  // scale * log2(e), folded into Q

  // ones fragment for the MFMA row-sum
  union U32x4 { unsigned u[4]; bf16x8 v; };
  U32x4 onesU;
  onesU.u[0] = onesU.u[1] = onesU.u[2] = onesU.u[3] = 0x3F803F80u;
  const bf16x8 onesf = onesU.v;

  // Q fragments in registers, pre-scaled (exp2 domain)
  bf16x8 qf[4];
  {
    const bf16* qp = Q + head + (size_t)qrow * D;
#pragma unroll
    for (int c = 0; c < 4; ++c) {
      bf16x8 t = *reinterpret_cast<const bf16x8*>(qp + c * 16 + hi * 8);
#pragma unroll
      for (int e = 0; e < 8; ++e) t[e] = (bf16)((float)t[e] * SC2);
      qf[c] = t;
    }
  }

  f32x16 accO0 = {}, accO1 = {}, accL = {};
  float mrun = -1e4f;

  auto stageK = [&](int t, int buf) {
#pragma unroll
    for (int j = 0; j < 2; ++j) {
      int c = (j * 4 + wave) * 64 + lane;  // chunk 0..511
      int r = c >> 3, ch = c & 7;
      int src = ((ch ^ (r & 7)) & 7) * 8;
      gload_lds16(&K[head + (size_t)(t * 64 + r) * D + src],
                  &Ks[buf][(j * 4 + wave) * 512]);
    }
  };
  auto loadV = [&](int t, bf16x8* vv) {
    int k0 = (tid & 31) * 2, d0 = (tid >> 5) * 8;
    vv[0] = *reinterpret_cast<const bf16x8*>(&V[head + (size_t)(t * 64 + k0) * D + d0]);
    vv[1] = *reinterpret_cast<const bf16x8*>(&V[head + (size_t)(t * 64 + k0 + 1) * D + d0]);
  };
  auto writeV = [&](const bf16x8* vv, int buf) {
    int k0 = (tid & 31) * 2, d0 = (tid >> 5) * 8;
#pragma unroll
    for (int e = 0; e < 8; ++e) {
      int row = d0 + e;
      int off = row * 64 + (((k0 >> 3) ^ (row & 7)) & 7) * 8 + (k0 & 7);
      union { unsigned u; bf16 h[2]; } pw;
      pw.h[0] = vv[0][e]; pw.h[1] = vv[1][e];
      *reinterpret_cast<unsigned*>(&Vt[buf][off]) = pw.u;
    }
  };

  const int nt = q0 / 64 + 2;

  {
    bf16x8 v0[2];
    loadV(0, v0);
    stageK(0, 0);
    writeV(v0, 0);
  }
  __syncthreads();

  int cur = 0;
  for (int t = 0; t < nt; ++t) {
    const int kv0 = t * 64;
    const bool more = (t + 1 < nt);
    bf16x8 vnext[2];
    if (more) {
      loadV(t + 1, vnext);       // oldest VMEM: counted wait for writeV
      stageK(t + 1, cur ^ 1);    // younger: drained only at the barrier
    }

    if (kv0 <= qw0 + 31) {  // tile contributes for this wave
      // ---- S^T = K Q^T ----
      f32x16 s0 = {}, s1 = {};
      __builtin_amdgcn_s_setprio(1);
#pragma unroll
      for (int c = 0; c < 4; ++c) {
        int r0 = ln, r1 = 32 + ln;
        int ch0 = ((2 * c + hi) ^ (r0 & 7)) & 7;
        int ch1 = ((2 * c + hi) ^ (r1 & 7)) & 7;
        bf16x8 kf0 = *reinterpret_cast<const bf16x8*>(&Ks[cur][r0 * 64 + ch0 * 8]);
        bf16x8 kf1 = *reinterpret_cast<const bf16x8*>(&Ks[cur][r1 * 64 + ch1 * 8]);
        s0 = MFMA32(kf0, qf[c], s0);
        s1 = MFMA32(kf1, qf[c], s1);
      }
      __builtin_amdgcn_s_setprio(0);

      if (kv0 + 63 > qw0) {  // diagonal: apply causal mask in place
#pragma unroll
        for (int r = 0; r < 16; ++r) {
          int kl = (r & 3) + 8 * (r >> 2) + 4 * hi;
          if (kv0 + kl > qrow) s0[r] = -1e30f;
          if (kv0 + 32 + kl > qrow) s1[r] = -1e30f;
        }
      }

      // ---- 3-ary max tree ----
      float t0 = mx3(s0[0], s0[1], s0[2]);
      float t1 = mx3(s0[3], s0[4], s0[5]);
      float t2 = mx3(s0[6], s0[7], s0[8]);
      float t3 = mx3(s0[9], s0[10], s0[11]);
      float t4 = mx3(s0[12], s0[13], s0[14]);
      float t5 = mx3(s0[15], s1[0], s1[1]);
      float t6 = mx3(s1[2], s1[3], s1[4]);
      float t7 = mx3(s1[5], s1[6], s1[7]);
      float t8 = mx3(s1[8], s1[9], s1[10]);
      float t9 = mx3(s1[11], s1[12], s1[13]);
      float ta = fmaxf(s1[14], s1[15]);
      float u0 = mx3(t0, t1, t2);
      float u1 = mx3(t3, t4, t5);
      float u2 = mx3(t6, t7, t8);
      float u3 = fmaxf(t9, ta);
      float pm = fmaxf(mx3(u0, u1, u2), u3);

      // defer-max: rescale only when max grew past THR=8
      if (!__all(pm - mrun <= 8.0f)) {
        float pm2 = fmaxf(pm, __shfl_xor(pm, 32));
        float mnew = fmaxf(mrun, pm2);
        float alpha = __builtin_amdgcn_exp2f(mrun - mnew);
        mrun = mnew;
        accL[0] *= alpha;
#pragma unroll
        for (int r = 0; r < 16; ++r) { accO0[r] *= alpha; accO1[r] *= alpha; }
      }

      float p[32];
#pragma unroll
      for (int r = 0; r < 16; ++r) {
        p[r] = __builtin_amdgcn_exp2f(s0[r] - mrun);
        p[16 + r] = __builtin_amdgcn_exp2f(s1[r] - mrun);
      }

      // ---- pack P to bf16 fragments in-register; PV + MFMA row-sum ----
      __builtin_amdgcn_s_setprio(1);
#pragma unroll
      for (int kg = 0; kg < 2; ++kg) {
        const float* pv = &p[kg * 16];
        unsigned w0 = pkbf(pv[0], pv[1]), w1 = pkbf(pv[2], pv[3]);
        unsigned w2 = pkbf(pv[4], pv[5]), w3 = pkbf(pv[6], pv[7]);
        unsigned w4 = pkbf(pv[8], pv[9]), w5 = pkbf(pv[10], pv[11]);
        unsigned w6 = pkbf(pv[12], pv[13]), w7 = pkbf(pv[14], pv[15]);
        union { unsigned u[4]; bf16x8 v; } fe, fo;
#if HAVE_PLSWAP
        uint2v r02 = __builtin_amdgcn_permlane32_swap(w0, w2, false, false);
        uint2v r13 = __builtin_amdgcn_permlane32_swap(w1, w3, false, false);
        uint2v r46 = __builtin_amdgcn_permlane32_swap(w4, w6, false, false);
        uint2v r57 = __builtin_amdgcn_permlane32_swap(w5, w7, false, false);
        fe.u[0] = r02.x; fe.u[1] = r13.x; fe.u[2] = r02.y; fe.u[3] = r13.y;
        fo.u[0] = r46.x; fo.u[1] = r57.x; fo.u[2] = r46.y; fo.u[3] = r57.y;
#else
        unsigned X0 = hi ? w0 : w2, X1 = hi ? w1 : w3;
        unsigned X2 = hi ? w4 : w6, X3 = hi ? w5 : w7;
        unsigned Y0 = __shfl_xor((int)X0, 32), Y1 = __shfl_xor((int)X1, 32);
        unsigned Y2 = __shfl_xor((int)X2, 32), Y3 = __shfl_xor((int)X3, 32);
        fe.u[0] = hi ? Y0 : w0; fe.u[1] = hi ? Y1 : w1;
        fe.u[2] = hi ? w2 : Y0; fe.u[3] = hi ? w3 : Y1;
        fo.u[0] = hi ? Y2 : w4; fo.u[1] = hi ? Y3 : w5;
        fo.u[2] = hi ? w6 : Y2; fo.u[3] = hi ? w7 : Y3;
#endif

#pragma unroll
        for (int half = 0; half < 2; ++half) {
          int kc = 2 * kg + half;
          bf16x8 pf = half ? fo.v : fe.v;
          int r0 = ln, r1 = 32 + ln;
          int ch0 = ((2 * kc + hi) ^ (r0 & 7)) & 7;
          int ch1 = ((2 * kc + hi) ^ (r1 & 7)) & 7;
          bf16x8 vf0 = *reinterpret_cast<const bf16x8*>(&Vt[cur][r0 * 64 + ch0 * 8]);
          bf16x8 vf1 = *reinterpret_cast<const bf16x8*>(&Vt[cur][r1 * 64 + ch1 * 8]);
          accO0 = MFMA32(vf0, pf, accO0);
          accO1 = MFMA32(vf1, pf, accO1);
          accL = MFMA32(onesf, pf, accL);  // row-sum on the MFMA pipe
        }
      }
      __builtin_amdgcn_s_setprio(0);
    }

    if (more) {
      writeV(vnext, cur ^ 1);  // waits only the 2 V loads (counted vmcnt)
      __syncthreads();
      cur ^= 1;
    }
  }

  // ---- epilogue ----
  float inv = 1.f / accL[0];
  bf16* yp = Y + head + (size_t)qrow * D;
#pragma unroll
  for (int g = 0; g < 4; ++g) {
    bf16x4 o0, o1;
#pragma unroll
    for (int i = 0; i < 4; ++i) {
      o0[i] = (bf16)(accO0[g * 4 + i] * inv);
      o1[i] = (bf16)(accO1[g * 4 + i] * inv);
    }
    *reinterpret_cast<bf16x4*>(yp + 8 * g + 4 * hi) = o0;
    *reinterpret_cast<bf16x4*>(yp + 32 + 8 * g + 4 * hi) = o1;
  }
}

// ---------------- launcher ----------------
extern "C" void kernel_launch(void* const* d_in, const int* in_sizes, int n_in,
                              void* d_out, int out_size, void* d_ws, size_t ws_size,
                              hipStream_t stream) {
  const float* x  = (const float*)d_in[0];
  const float* Wq = (const float*)d_in[1];
  const float* bq = (const float*)d_in[2];
  const float* Wk = (const float*)d_in[3];
  const float* bk = (const float*)d_in[4];
  const float* Wv = (const float*)d_in[5];
  const float* bv = (const float*)d_in[6];
  const float* Wo = (const float*)d_in[7];
  const float* bo = (const float*)d_in[8];
  float* out = (float*)d_out;

  constexpr int Bx = 2, S = 4096, Dd = 768;
  constexpr int M = Bx * S;                   // 8192
  constexpr size_t XB = (size_t)M * Dd;       // 6291456 elems
  constexpr size_t WB = (size_t)Dd * Dd;      // 589824 elems

  char* ws = (char*)d_ws;
  bf16* xb = (bf16*)ws;                        // XB elems
  bf16* Wb = (bf16*)(ws + 2 * XB);             // 4*WB elems (Wq,Wk,Wv,Wo)
  bf16* Qb = (bf16*)(ws + 2 * XB + 8 * WB);    // XB
  bf16* Kb = Qb + XB;
  bf16* Vb = Kb + XB;
  bf16* Yb = Vb + XB;

  cvt_all<<<2048, 256, 0, stream>>>(x, Wq, Wk, Wv, Wo, xb, Wb);

  // fused Q/K/V projections (z = 0,1,2), bf16 out
  gemm_bt<true><<<dim3(6, 64, 3), 256, 0, stream>>>(
      xb, Wb, bq, bk, bv, nullptr, Qb, M, Dd, Dd);

  // attention (32x32 swapped structure)
  attn32<<<dim3(S / 128, 12, Bx), 256, 0, stream>>>(Qb, Kb, Vb, Yb);

  // output projection, f32 out
  gemm_bt<false><<<dim3(6, 64, 1), 256, 0, stream>>>(
      Yb, Wb + 3 * WB, bo, bo, bo, out, nullptr, M, Dd, Dd);
}

// Round 6
// 209.411 us; speedup vs baseline: 2.1330x; 1.0289x over previous
//
#include <hip/hip_runtime.h>
#include <hip/hip_bf16.h>

typedef __bf16 bf16;
typedef __attribute__((ext_vector_type(8))) __bf16 bf16x8;
typedef __attribute__((ext_vector_type(4))) __bf16 bf16x4;
typedef __attribute__((ext_vector_type(4))) float f32x4;
typedef __attribute__((ext_vector_type(16))) float f32x16;

#if __has_builtin(__builtin_amdgcn_permlane32_swap)
#define HAVE_PLSWAP 1
typedef __attribute__((ext_vector_type(2))) unsigned uint2v;
#endif

#define MFMA16(a, b, c) __builtin_amdgcn_mfma_f32_16x16x32_bf16((a), (b), (c), 0, 0, 0)
#define MFMA32(a, b, c) __builtin_amdgcn_mfma_f32_32x32x16_bf16((a), (b), (c), 0, 0, 0)

__device__ __forceinline__ void gload_lds16(const bf16* g, bf16* l) {
  __builtin_amdgcn_global_load_lds(
      (const __attribute__((address_space(1))) void*)g,
      (__attribute__((address_space(3))) void*)l, 16, 0, 0);
}

__device__ __forceinline__ unsigned pkbf(float a, float b) {
  union { unsigned u; bf16 h[2]; } w;
  w.h[0] = (bf16)a; w.h[1] = (bf16)b;
  return w.u;
}

__device__ __forceinline__ float mx3(float a, float b, float c) {
  return fmaxf(fmaxf(a, b), c);
}

// ---------------- fused f32 -> bf16 conversion ----------------
__global__ void cvt_all(const float* __restrict__ x,
                        const float* __restrict__ wq, const float* __restrict__ wk,
                        const float* __restrict__ wv, const float* __restrict__ wo,
                        bf16* __restrict__ xb, bf16* __restrict__ Wb) {
  constexpr int NX4 = 6291456 / 4;
  constexpr int NW4 = 589824 / 4;
  constexpr int TOT = NX4 + 4 * NW4;
  int stride = gridDim.x * blockDim.x;
  for (int i = blockIdx.x * blockDim.x + threadIdx.x; i < TOT; i += stride) {
    const float4* src;
    bf16x4* dst;
    if (i < NX4) {
      src = reinterpret_cast<const float4*>(x) + i;
      dst = reinterpret_cast<bf16x4*>(xb) + i;
    } else {
      int j = i - NX4;
      int w = j / NW4, r = j - w * NW4;
      const float* sp = (w == 0) ? wq : (w == 1) ? wk : (w == 2) ? wv : wo;
      src = reinterpret_cast<const float4*>(sp) + r;
      dst = reinterpret_cast<bf16x4*>(Wb) + j;
    }
    float4 v = *src;
    bf16x4 o = {(bf16)v.x, (bf16)v.y, (bf16)v.z, (bf16)v.w};
    *dst = o;
  }
}

// ---------------- GEMM: C[M,N] = A[M,K] * W[N,K]^T + bias, BK=64 ----------------
template <bool OUT_BF16>
__global__ __launch_bounds__(256) void gemm_bt(
    const bf16* __restrict__ A, const bf16* __restrict__ W,
    const float* __restrict__ b0, const float* __restrict__ b1, const float* __restrict__ b2,
    float* __restrict__ Cf, bf16* __restrict__ Cb,
    int M, int N, int K) {
  const int z = blockIdx.z;
  const bf16* Wz = W + (size_t)z * N * K;
  const float* bias = (z == 0) ? b0 : (z == 1 ? b1 : b2);

  __shared__ alignas(16) bf16 As[128 * 64];
  __shared__ alignas(16) bf16 Bs[128 * 64];

  const int tid = threadIdx.x;
  const int wave = tid >> 6, lane = tid & 63;
  const int lr = lane & 15, lg = lane >> 4;
  const int wr = wave >> 1, wc = wave & 1;
  const int m0 = blockIdx.y * 128, n0 = blockIdx.x * 128;

  f32x4 acc[4][4] = {};

  for (int k0 = 0; k0 < K; k0 += 64) {
    __syncthreads();
#pragma unroll
    for (int j = 0; j < 4; ++j) {
      int cb = j * 256 + wave * 64;
      int c = cb + lane;
      int row = c >> 3, x = c & 7;
      int xs = x ^ (row & 7);
      gload_lds16(&A[(size_t)(m0 + row) * K + k0 + xs * 8], &As[cb * 8]);
      gload_lds16(&Wz[(size_t)(n0 + row) * K + k0 + xs * 8], &Bs[cb * 8]);
    }
    __syncthreads();
#pragma unroll
    for (int kk = 0; kk < 2; ++kk) {
      bf16x8 af[4], bfr[4];
#pragma unroll
      for (int m = 0; m < 4; ++m) {
        int row = wr * 64 + m * 16 + lr;
        int ch = (kk * 4 + lg) ^ (row & 7);
        af[m] = *reinterpret_cast<const bf16x8*>(&As[row * 64 + ch * 8]);
      }
#pragma unroll
      for (int n = 0; n < 4; ++n) {
        int row = wc * 64 + n * 16 + lr;
        int ch = (kk * 4 + lg) ^ (row & 7);
        bfr[n] = *reinterpret_cast<const bf16x8*>(&Bs[row * 64 + ch * 8]);
      }
      __builtin_amdgcn_s_setprio(1);
#pragma unroll
      for (int m = 0; m < 4; ++m)
#pragma unroll
        for (int n = 0; n < 4; ++n)
          acc[m][n] = MFMA16(af[m], bfr[n], acc[m][n]);
      __builtin_amdgcn_s_setprio(0);
    }
  }

#pragma unroll
  for (int m = 0; m < 4; ++m) {
#pragma unroll
    for (int n = 0; n < 4; ++n) {
#pragma unroll
      for (int i = 0; i < 4; ++i) {
        int row = m0 + wr * 64 + m * 16 + lg * 4 + i;
        int col = n0 + wc * 64 + n * 16 + lr;
        float v = acc[m][n][i] + bias[col];
        if constexpr (OUT_BF16)
          (Cb + (size_t)z * M * N)[(size_t)row * N + col] = (bf16)v;
        else
          Cf[(size_t)row * N + col] = v;
      }
    }
  }
}

// ---------------- causal flash attention, 32x32 swapped-QK ----------------
__global__ __launch_bounds__(256, 3) void attn32(
    const bf16* __restrict__ Q, const bf16* __restrict__ K,
    const bf16* __restrict__ V, bf16* __restrict__ Y) {
  constexpr int S = 4096, D = 768;
  // XCD-affine remap: each (h,bb) pair's 32 q-blocks stay on one XCD,
  // q-tiles in descending length within each stream.
  const int lin = blockIdx.x + 32 * blockIdx.y + 384 * blockIdx.z;
  const int xcd = lin & 7, idx = lin >> 3;       // 96 blocks per XCD
  const int pair = xcd * 3 + (idx >> 5);         // 0..23
  const int qb = 31 - (idx & 31);
  const int h = pair % 12, bb = pair / 12;

  const int tid = threadIdx.x, wave = tid >> 6, lane = tid & 63;
  const int ln = lane & 31, hi = lane >> 5;
  const int q0 = qb * 128;
  const int qw0 = q0 + wave * 32;
  const int qrow = qw0 + ln;

  __shared__ alignas(16) bf16 Ks[2][64 * 64];  // [buf], row*64, chunk^=(row&7)
  __shared__ alignas(16) bf16 Vt[2][64 * 64];  // [buf] V^T, same swizzle

  const size_t head = (size_t)bb * S * D + (size_t)h * 64;
  const float SC2 = 0.125f * 1.44269504089f;

  union U32x4 { unsigned u[4]; bf16x8 v; };
  U32x4 onesU;
  onesU.u[0] = onesU.u[1] = onesU.u[2] = onesU.u[3] = 0x3F803F80u;
  const bf16x8 onesf = onesU.v;

  // Q fragments, pre-scaled (exp2 domain)
  bf16x8 qf[4];
  {
    const bf16* qp = Q + head + (size_t)qrow * D;
#pragma unroll
    for (int c = 0; c < 4; ++c) {
      bf16x8 t = *reinterpret_cast<const bf16x8*>(qp + c * 16 + hi * 8);
#pragma unroll
      for (int e = 0; e < 8; ++e) t[e] = (bf16)((float)t[e] * SC2);
      qf[c] = t;
    }
  }

  // ---- loop-invariant per-lane offsets ----
  // K/V fragment reads (same formula for both): second 32 rows = +2048 elems
  int fOff[4];
#pragma unroll
  for (int i = 0; i < 4; ++i)
    fOff[i] = ln * 64 + ((((2 * i + hi) ^ ln) & 7) * 8);

  // writeV: d0 rows, paired-k b32 writes
  const int d0 = (tid >> 5) * 8, k0v = ln * 2;
  int wOff[8];
#pragma unroll
  for (int e = 0; e < 8; ++e)
    wOff[e] = (d0 + e) * 64 + ((((ln >> 2) ^ e) & 7) * 8) + (k0v & 7);

  // stageK: per-lane global offsets + wave-uniform LDS chunk bases
  const bf16* gk[2];
  int ldsK[2];
#pragma unroll
  for (int j = 0; j < 2; ++j) {
    int c = (j * 4 + wave) * 64 + lane;
    int r = c >> 3;
    int src = (((lane ^ r) & 7)) * 8;  // ch = lane&7
    gk[j] = K + head + (size_t)r * D + src;
    ldsK[j] = (j * 4 + wave) * 512;
  }
  // loadV: rows k0v, k0v+1 at col d0
  const bf16* gv0 = V + head + (size_t)k0v * D + d0;
  const bf16* gv1 = gv0 + D;

  f32x16 accO0 = {}, accO1 = {}, accL = {};
  float mrun = 8.0f;  // exp2-domain; data max ~7.5 -> common path never rescales

  auto stageK = [&](int buf) {
#pragma unroll
    for (int j = 0; j < 2; ++j) {
      gload_lds16(gk[j], &Ks[buf][ldsK[j]]);
      gk[j] += 64 * D;
    }
  };
  auto loadV = [&](bf16x8* vv) {
    vv[0] = *reinterpret_cast<const bf16x8*>(gv0);
    vv[1] = *reinterpret_cast<const bf16x8*>(gv1);
    gv0 += 64 * D;
    gv1 += 64 * D;
  };
  auto writeV = [&](const bf16x8* vv, int buf) {
#pragma unroll
    for (int e = 0; e < 8; ++e) {
      union { unsigned u; bf16 h[2]; } pw;
      pw.h[0] = vv[0][e]; pw.h[1] = vv[1][e];
      *reinterpret_cast<unsigned*>(&Vt[buf][wOff[e]]) = pw.u;
    }
  };

  const int nt = q0 / 64 + 2;

  {
    bf16x8 v0[2];
    loadV(v0);
    stageK(0);
    writeV(v0, 0);
  }
  __syncthreads();

  int cur = 0;
  for (int t = 0; t < nt; ++t) {
    const int kv0 = t * 64;
    const bool more = (t + 1 < nt);
    bf16x8 vnext[2];
    if (more) {
      loadV(vnext);       // oldest VMEM -> counted wait in writeV
      stageK(cur ^ 1);    // drained at barrier only
    }

    if (kv0 <= qw0 + 31) {
      // ---- S^T = K Q^T ----
      f32x16 s0 = {}, s1 = {};
      __builtin_amdgcn_s_setprio(1);
#pragma unroll
      for (int c = 0; c < 4; ++c) {
        bf16x8 kf0 = *reinterpret_cast<const bf16x8*>(&Ks[cur][fOff[c]]);
        bf16x8 kf1 = *reinterpret_cast<const bf16x8*>(&Ks[cur][fOff[c] + 2048]);
        s0 = MFMA32(kf0, qf[c], s0);
        s1 = MFMA32(kf1, qf[c], s1);
      }
      __builtin_amdgcn_s_setprio(0);

      if (kv0 + 63 > qw0) {  // diagonal: causal mask in place
#pragma unroll
        for (int r = 0; r < 16; ++r) {
          int kl = (r & 3) + 8 * (r >> 2) + 4 * hi;
          if (kv0 + kl > qrow) s0[r] = -1e30f;
          if (kv0 + 32 + kl > qrow) s1[r] = -1e30f;
        }
      }

      // ---- exp FIRST with stale mrun (defer-max); max tree runs in parallel ----
      float p[32];
#pragma unroll
      for (int r = 0; r < 16; ++r) {
        p[r] = __builtin_amdgcn_exp2f(s0[r] - mrun);
        p[16 + r] = __builtin_amdgcn_exp2f(s1[r] - mrun);
      }

      float t0 = mx3(s0[0], s0[1], s0[2]);
      float t1 = mx3(s0[3], s0[4], s0[5]);
      float t2 = mx3(s0[6], s0[7], s0[8]);
      float t3 = mx3(s0[9], s0[10], s0[11]);
      float t4 = mx3(s0[12], s0[13], s0[14]);
      float t5 = mx3(s0[15], s1[0], s1[1]);
      float t6 = mx3(s1[2], s1[3], s1[4]);
      float t7 = mx3(s1[5], s1[6], s1[7]);
      float t8 = mx3(s1[8], s1[9], s1[10]);
      float t9 = mx3(s1[11], s1[12], s1[13]);
      float ta = fmaxf(s1[14], s1[15]);
      float u0 = mx3(t0, t1, t2);
      float u1 = mx3(t3, t4, t5);
      float u2 = mx3(t6, t7, t8);
      float u3 = fmaxf(t9, ta);
      float pm = fmaxf(mx3(u0, u1, u2), u3);

      if (!__all(pm - mrun <= 8.0f)) {  // rare: rescale everything incl. fresh p
        float pm2 = fmaxf(pm, __shfl_xor(pm, 32));
        float mnew = fmaxf(mrun, pm2);
        float alpha = __builtin_amdgcn_exp2f(mrun - mnew);
        mrun = mnew;
        accL[0] *= alpha;
#pragma unroll
        for (int r = 0; r < 16; ++r) {
          accO0[r] *= alpha; accO1[r] *= alpha;
          p[r] *= alpha; p[16 + r] *= alpha;
        }
      }

      // ---- pack P in-register; PV + MFMA row-sum ----
      __builtin_amdgcn_s_setprio(1);
#pragma unroll
      for (int kg = 0; kg < 2; ++kg) {
        const float* pv = &p[kg * 16];
        unsigned w0 = pkbf(pv[0], pv[1]), w1 = pkbf(pv[2], pv[3]);
        unsigned w2 = pkbf(pv[4], pv[5]), w3 = pkbf(pv[6], pv[7]);
        unsigned w4 = pkbf(pv[8], pv[9]), w5 = pkbf(pv[10], pv[11]);
        unsigned w6 = pkbf(pv[12], pv[13]), w7 = pkbf(pv[14], pv[15]);
        union { unsigned u[4]; bf16x8 v; } fe, fo;
#if HAVE_PLSWAP
        uint2v r02 = __builtin_amdgcn_permlane32_swap(w0, w2, false, false);
        uint2v r13 = __builtin_amdgcn_permlane32_swap(w1, w3, false, false);
        uint2v r46 = __builtin_amdgcn_permlane32_swap(w4, w6, false, false);
        uint2v r57 = __builtin_amdgcn_permlane32_swap(w5, w7, false, false);
        fe.u[0] = r02.x; fe.u[1] = r13.x; fe.u[2] = r02.y; fe.u[3] = r13.y;
        fo.u[0] = r46.x; fo.u[1] = r57.x; fo.u[2] = r46.y; fo.u[3] = r57.y;
#else
        unsigned X0 = hi ? w0 : w2, X1 = hi ? w1 : w3;
        unsigned X2 = hi ? w4 : w6, X3 = hi ? w5 : w7;
        unsigned Y0 = __shfl_xor((int)X0, 32), Y1 = __shfl_xor((int)X1, 32);
        unsigned Y2 = __shfl_xor((int)X2, 32), Y3 = __shfl_xor((int)X3, 32);
        fe.u[0] = hi ? Y0 : w0; fe.u[1] = hi ? Y1 : w1;
        fe.u[2] = hi ? w2 : Y0; fe.u[3] = hi ? w3 : Y1;
        fo.u[0] = hi ? Y2 : w4; fo.u[1] = hi ? Y3 : w5;
        fo.u[2] = hi ? w6 : Y2; fo.u[3] = hi ? w7 : Y3;
#endif
#pragma unroll
        for (int half = 0; half < 2; ++half) {
          int kc = 2 * kg + half;
          bf16x8 pf = half ? fo.v : fe.v;
          bf16x8 vf0 = *reinterpret_cast<const bf16x8*>(&Vt[cur][fOff[kc]]);
          bf16x8 vf1 = *reinterpret_cast<const bf16x8*>(&Vt[cur][fOff[kc] + 2048]);
          accO0 = MFMA32(vf0, pf, accO0);
          accO1 = MFMA32(vf1, pf, accO1);
          accL = MFMA32(onesf, pf, accL);
        }
      }
      __builtin_amdgcn_s_setprio(0);
    }

    if (more) {
      writeV(vnext, cur ^ 1);
      __syncthreads();
      cur ^= 1;
    }
  }

  // ---- epilogue ----
  float inv = 1.f / accL[0];
  bf16* yp = Y + head + (size_t)qrow * D;
#pragma unroll
  for (int g = 0; g < 4; ++g) {
    bf16x4 o0, o1;
#pragma unroll
    for (int i = 0; i < 4; ++i) {
      o0[i] = (bf16)(accO0[g * 4 + i] * inv);
      o1[i] = (bf16)(accO1[g * 4 + i] * inv);
    }
    *reinterpret_cast<bf16x4*>(yp + 8 * g + 4 * hi) = o0;
    *reinterpret_cast<bf16x4*>(yp + 32 + 8 * g + 4 * hi) = o1;
  }
}

// ---------------- launcher ----------------
extern "C" void kernel_launch(void* const* d_in, const int* in_sizes, int n_in,
                              void* d_out, int out_size, void* d_ws, size_t ws_size,
                              hipStream_t stream) {
  const float* x  = (const float*)d_in[0];
  const float* Wq = (const float*)d_in[1];
  const float* bq = (const float*)d_in[2];
  const float* Wk = (const float*)d_in[3];
  const float* bk = (const float*)d_in[4];
  const float* Wv = (const float*)d_in[5];
  const float* bv = (const float*)d_in[6];
  const float* Wo = (const float*)d_in[7];
  const float* bo = (const float*)d_in[8];
  float* out = (float*)d_out;

  constexpr int Bx = 2, S = 4096, Dd = 768;
  constexpr int M = Bx * S;
  constexpr size_t XB = (size_t)M * Dd;
  constexpr size_t WB = (size_t)Dd * Dd;

  char* ws = (char*)d_ws;
  bf16* xb = (bf16*)ws;
  bf16* Wb = (bf16*)(ws + 2 * XB);
  bf16* Qb = (bf16*)(ws + 2 * XB + 8 * WB);
  bf16* Kb = Qb + XB;
  bf16* Vb = Kb + XB;
  bf16* Yb = Vb + XB;

  cvt_all<<<2048, 256, 0, stream>>>(x, Wq, Wk, Wv, Wo, xb, Wb);

  gemm_bt<true><<<dim3(6, 64, 3), 256, 0, stream>>>(
      xb, Wb, bq, bk, bv, nullptr, Qb, M, Dd, Dd);

  attn32<<<dim3(S / 128, 12, Bx), 256, 0, stream>>>(Qb, Kb, Vb, Yb);

  gemm_bt<false><<<dim3(6, 64, 1), 256, 0, stream>>>(
      Yb, Wb + 3 * WB, bo, bo, bo, out, nullptr, M, Dd, Dd);
}

// Round 7
// 196.568 us; speedup vs baseline: 2.2723x; 1.0653x over previous
//
#include <hip/hip_runtime.h>
#include <hip/hip_bf16.h>

typedef __bf16 bf16;
typedef __attribute__((ext_vector_type(8))) __bf16 bf16x8;
typedef __attribute__((ext_vector_type(4))) __bf16 bf16x4;
typedef __attribute__((ext_vector_type(4))) float f32x4;
typedef __attribute__((ext_vector_type(16))) float f32x16;

#if __has_builtin(__builtin_amdgcn_permlane32_swap)
#define HAVE_PLSWAP 1
typedef __attribute__((ext_vector_type(2))) unsigned uint2v;
#endif

#define MFMA16(a, b, c) __builtin_amdgcn_mfma_f32_16x16x32_bf16((a), (b), (c), 0, 0, 0)
#define MFMA32(a, b, c) __builtin_amdgcn_mfma_f32_32x32x16_bf16((a), (b), (c), 0, 0, 0)

__device__ __forceinline__ void gload_lds16(const bf16* g, bf16* l) {
  __builtin_amdgcn_global_load_lds(
      (const __attribute__((address_space(1))) void*)g,
      (__attribute__((address_space(3))) void*)l, 16, 0, 0);
}

__device__ __forceinline__ unsigned pkbf(float a, float b) {
  union { unsigned u; bf16 h[2]; } w;
  w.h[0] = (bf16)a; w.h[1] = (bf16)b;
  return w.u;
}

__device__ __forceinline__ float mx3(float a, float b, float c) {
  return fmaxf(fmaxf(a, b), c);
}

// ---------------- fused f32 -> bf16 conversion ----------------
__global__ void cvt_all(const float* __restrict__ x,
                        const float* __restrict__ wq, const float* __restrict__ wk,
                        const float* __restrict__ wv, const float* __restrict__ wo,
                        bf16* __restrict__ xb, bf16* __restrict__ Wb) {
  constexpr int NX4 = 6291456 / 4;
  constexpr int NW4 = 589824 / 4;
  constexpr int TOT = NX4 + 4 * NW4;
  int stride = gridDim.x * blockDim.x;
  for (int i = blockIdx.x * blockDim.x + threadIdx.x; i < TOT; i += stride) {
    const float4* src;
    bf16x4* dst;
    if (i < NX4) {
      src = reinterpret_cast<const float4*>(x) + i;
      dst = reinterpret_cast<bf16x4*>(xb) + i;
    } else {
      int j = i - NX4;
      int w = j / NW4, r = j - w * NW4;
      const float* sp = (w == 0) ? wq : (w == 1) ? wk : (w == 2) ? wv : wo;
      src = reinterpret_cast<const float4*>(sp) + r;
      dst = reinterpret_cast<bf16x4*>(Wb) + j;
    }
    float4 v = *src;
    bf16x4 o = {(bf16)v.x, (bf16)v.y, (bf16)v.z, (bf16)v.w};
    *dst = o;
  }
}

// ---------------- GEMM: C[M,N] = A[M,K] * W[N,K]^T + bias, BK=64 ----------------
template <bool OUT_BF16>
__global__ __launch_bounds__(256) void gemm_bt(
    const bf16* __restrict__ A, const bf16* __restrict__ W,
    const float* __restrict__ b0, const float* __restrict__ b1, const float* __restrict__ b2,
    float* __restrict__ Cf, bf16* __restrict__ Cb,
    int M, int N, int K) {
  const int z = blockIdx.z;
  const bf16* Wz = W + (size_t)z * N * K;
  const float* bias = (z == 0) ? b0 : (z == 1 ? b1 : b2);

  __shared__ alignas(16) bf16 As[128 * 64];
  __shared__ alignas(16) bf16 Bs[128 * 64];

  const int tid = threadIdx.x;
  const int wave = tid >> 6, lane = tid & 63;
  const int lr = lane & 15, lg = lane >> 4;
  const int wr = wave >> 1, wc = wave & 1;
  const int m0 = blockIdx.y * 128, n0 = blockIdx.x * 128;

  f32x4 acc[4][4] = {};

  for (int k0 = 0; k0 < K; k0 += 64) {
    __syncthreads();
#pragma unroll
    for (int j = 0; j < 4; ++j) {
      int cb = j * 256 + wave * 64;
      int c = cb + lane;
      int row = c >> 3, x = c & 7;
      int xs = x ^ (row & 7);
      gload_lds16(&A[(size_t)(m0 + row) * K + k0 + xs * 8], &As[cb * 8]);
      gload_lds16(&Wz[(size_t)(n0 + row) * K + k0 + xs * 8], &Bs[cb * 8]);
    }
    __syncthreads();
#pragma unroll
    for (int kk = 0; kk < 2; ++kk) {
      bf16x8 af[4], bfr[4];
#pragma unroll
      for (int m = 0; m < 4; ++m) {
        int row = wr * 64 + m * 16 + lr;
        int ch = (kk * 4 + lg) ^ (row & 7);
        af[m] = *reinterpret_cast<const bf16x8*>(&As[row * 64 + ch * 8]);
      }
#pragma unroll
      for (int n = 0; n < 4; ++n) {
        int row = wc * 64 + n * 16 + lr;
        int ch = (kk * 4 + lg) ^ (row & 7);
        bfr[n] = *reinterpret_cast<const bf16x8*>(&Bs[row * 64 + ch * 8]);
      }
      __builtin_amdgcn_s_setprio(1);
#pragma unroll
      for (int m = 0; m < 4; ++m)
#pragma unroll
        for (int n = 0; n < 4; ++n)
          acc[m][n] = MFMA16(af[m], bfr[n], acc[m][n]);
      __builtin_amdgcn_s_setprio(0);
    }
  }

#pragma unroll
  for (int m = 0; m < 4; ++m) {
#pragma unroll
    for (int n = 0; n < 4; ++n) {
#pragma unroll
      for (int i = 0; i < 4; ++i) {
        int row = m0 + wr * 64 + m * 16 + lg * 4 + i;
        int col = n0 + wc * 64 + n * 16 + lr;
        float v = acc[m][n][i] + bias[col];
        if constexpr (OUT_BF16)
          (Cb + (size_t)z * M * N)[(size_t)row * N + col] = (bf16)v;
        else
          Cf[(size_t)row * N + col] = v;
      }
    }
  }
}

// ---------------- causal flash attention: 64-row strips, 2-wave blocks ----------------
// grid: 1536 blocks x 128 threads. Per (b,h): 64 strips; strip qs does qs+1 KV tiles.
// 32 KB LDS -> 5 blocks/CU resident, 1536 > 1280 slots -> backfill; longest-first per XCD.
__global__ __launch_bounds__(128, 2) void attn32(
    const bf16* __restrict__ Q, const bf16* __restrict__ K,
    const bf16* __restrict__ V, bf16* __restrict__ Y) {
  constexpr int S = 4096, D = 768;
  // XCD-affine remap: lin&7 = XCD; each XCD owns 3 (b,h) pairs; strips descending.
  const int lin = blockIdx.x;
  const int xcd = lin & 7, idx = lin >> 3;      // idx 0..191
  const int pair = xcd * 3 + (idx >> 6);        // 0..23
  const int qs = 63 - (idx & 63);               // strip, longest work first
  const int h = pair % 12, bb = pair / 12;

  const int tid = threadIdx.x, wave = tid >> 6, lane = tid & 63;
  const int ln = lane & 31, hi = lane >> 5;
  const int q0s = qs * 64;
  const int qw0 = q0s + wave * 32;
  const int qrow = qw0 + ln;

  __shared__ alignas(16) bf16 Ks[2][64 * 64];  // [buf], row*64, chunk^=(row&7)
  __shared__ alignas(16) bf16 Vt[2][64 * 64];  // [buf] V^T, same swizzle

  const size_t head = (size_t)bb * S * D + (size_t)h * 64;
  const float SC2 = 0.125f * 1.44269504089f;

  union U32x4 { unsigned u[4]; bf16x8 v; };
  U32x4 onesU;
  onesU.u[0] = onesU.u[1] = onesU.u[2] = onesU.u[3] = 0x3F803F80u;
  const bf16x8 onesf = onesU.v;

  // Q fragments, pre-scaled (exp2 domain)
  bf16x8 qf[4];
  {
    const bf16* qp = Q + head + (size_t)qrow * D;
#pragma unroll
    for (int c = 0; c < 4; ++c) {
      bf16x8 t = *reinterpret_cast<const bf16x8*>(qp + c * 16 + hi * 8);
#pragma unroll
      for (int e = 0; e < 8; ++e) t[e] = (bf16)((float)t[e] * SC2);
      qf[c] = t;
    }
  }

  // ---- loop-invariant offsets ----
  int fOff[4];
#pragma unroll
  for (int i = 0; i < 4; ++i)
    fOff[i] = ln * 64 + ((((2 * i + hi) ^ ln) & 7) * 8);

  // stageK: 4 chunks/lane (512 chunks over 128 threads)
  const bf16* gk[4];
  int ldsK[4];
#pragma unroll
  for (int j = 0; j < 4; ++j) {
    int c = j * 128 + tid;
    int r = c >> 3, ch = c & 7;
    gk[j] = K + head + (size_t)r * D + ((ch ^ (r & 7)) & 7) * 8;
    ldsK[j] = (j * 128 + wave * 64) * 8;  // wave-uniform elem base
  }

  // loadV/writeV: lane owns rows k0v..k0v+3 at col-group d0
  const int k0v = (tid & 15) * 4, d0 = (tid >> 4) * 8;
  const bf16* gv[4];
#pragma unroll
  for (int m = 0; m < 4; ++m) gv[m] = V + head + (size_t)(k0v + m) * D + d0;
  int wOff[8];
#pragma unroll
  for (int e = 0; e < 8; ++e)
    wOff[e] = (d0 + e) * 64 + ((((k0v >> 3) ^ e) & 7) * 8) + (k0v & 7);

  f32x16 accO0 = {}, accO1 = {}, accL = {};
  float mrun = 8.0f;  // exp2-domain stale max (defer-max)

  auto stageK = [&](int buf) {
#pragma unroll
    for (int j = 0; j < 4; ++j) {
      gload_lds16(gk[j], &Ks[buf][ldsK[j]]);
      gk[j] += 64 * D;
    }
  };
  auto loadV = [&](bf16x8* vv) {
#pragma unroll
    for (int m = 0; m < 4; ++m) {
      vv[m] = *reinterpret_cast<const bf16x8*>(gv[m]);
      gv[m] += 64 * D;
    }
  };
  auto writeV = [&](const bf16x8* vv, int buf) {
#pragma unroll
    for (int e = 0; e < 8; ++e) {
      bf16x4 pw = {vv[0][e], vv[1][e], vv[2][e], vv[3][e]};
      *reinterpret_cast<bf16x4*>(&Vt[buf][wOff[e]]) = pw;  // ds_write_b64
    }
  };

  const int nt = qs + 1;

  {
    bf16x8 v0[4];
    loadV(v0);
    stageK(0);
    writeV(v0, 0);
  }
  __syncthreads();

  int cur = 0;
  for (int t = 0; t < nt; ++t) {
    const int kv0 = t * 64;
    const bool more = (t + 1 < nt);
    bf16x8 vnext[4];
    if (more) {
      loadV(vnext);       // oldest VMEM -> counted wait in writeV
      stageK(cur ^ 1);    // drained at barrier only
    }

    // ---- S^T = K Q^T ----
    f32x16 s0 = {}, s1 = {};
    __builtin_amdgcn_s_setprio(1);
#pragma unroll
    for (int c = 0; c < 4; ++c) {
      bf16x8 kf0 = *reinterpret_cast<const bf16x8*>(&Ks[cur][fOff[c]]);
      bf16x8 kf1 = *reinterpret_cast<const bf16x8*>(&Ks[cur][fOff[c] + 2048]);
      s0 = MFMA32(kf0, qf[c], s0);
      s1 = MFMA32(kf1, qf[c], s1);
    }
    __builtin_amdgcn_s_setprio(0);

    if (kv0 + 63 > qw0) {  // diagonal: causal mask in place
#pragma unroll
      for (int r = 0; r < 16; ++r) {
        int kl = (r & 3) + 8 * (r >> 2) + 4 * hi;
        if (kv0 + kl > qrow) s0[r] = -1e30f;
        if (kv0 + 32 + kl > qrow) s1[r] = -1e30f;
      }
    }

    // ---- exp first with stale mrun; max tree off critical path ----
    float p[32];
#pragma unroll
    for (int r = 0; r < 16; ++r) {
      p[r] = __builtin_amdgcn_exp2f(s0[r] - mrun);
      p[16 + r] = __builtin_amdgcn_exp2f(s1[r] - mrun);
    }

    float t0 = mx3(s0[0], s0[1], s0[2]);
    float t1 = mx3(s0[3], s0[4], s0[5]);
    float t2 = mx3(s0[6], s0[7], s0[8]);
    float t3 = mx3(s0[9], s0[10], s0[11]);
    float t4 = mx3(s0[12], s0[13], s0[14]);
    float t5 = mx3(s0[15], s1[0], s1[1]);
    float t6 = mx3(s1[2], s1[3], s1[4]);
    float t7 = mx3(s1[5], s1[6], s1[7]);
    float t8 = mx3(s1[8], s1[9], s1[10]);
    float t9 = mx3(s1[11], s1[12], s1[13]);
    float ta = fmaxf(s1[14], s1[15]);
    float u0 = mx3(t0, t1, t2);
    float u1 = mx3(t3, t4, t5);
    float u2 = mx3(t6, t7, t8);
    float u3 = fmaxf(t9, ta);
    float pm = fmaxf(mx3(u0, u1, u2), u3);

    if (!__all(pm - mrun <= 8.0f)) {  // rare: rescale everything incl. fresh p
      float pm2 = fmaxf(pm, __shfl_xor(pm, 32));
      float mnew = fmaxf(mrun, pm2);
      float alpha = __builtin_amdgcn_exp2f(mrun - mnew);
      mrun = mnew;
      accL[0] *= alpha;
#pragma unroll
      for (int r = 0; r < 16; ++r) {
        accO0[r] *= alpha; accO1[r] *= alpha;
        p[r] *= alpha; p[16 + r] *= alpha;
      }
    }

    // ---- pack P in-register; PV + MFMA row-sum ----
    __builtin_amdgcn_s_setprio(1);
#pragma unroll
    for (int kg = 0; kg < 2; ++kg) {
      const float* pv = &p[kg * 16];
      unsigned w0 = pkbf(pv[0], pv[1]), w1 = pkbf(pv[2], pv[3]);
      unsigned w2 = pkbf(pv[4], pv[5]), w3 = pkbf(pv[6], pv[7]);
      unsigned w4 = pkbf(pv[8], pv[9]), w5 = pkbf(pv[10], pv[11]);
      unsigned w6 = pkbf(pv[12], pv[13]), w7 = pkbf(pv[14], pv[15]);
      union { unsigned u[4]; bf16x8 v; } fe, fo;
#if HAVE_PLSWAP
      uint2v r02 = __builtin_amdgcn_permlane32_swap(w0, w2, false, false);
      uint2v r13 = __builtin_amdgcn_permlane32_swap(w1, w3, false, false);
      uint2v r46 = __builtin_amdgcn_permlane32_swap(w4, w6, false, false);
      uint2v r57 = __builtin_amdgcn_permlane32_swap(w5, w7, false, false);
      fe.u[0] = r02.x; fe.u[1] = r13.x; fe.u[2] = r02.y; fe.u[3] = r13.y;
      fo.u[0] = r46.x; fo.u[1] = r57.x; fo.u[2] = r46.y; fo.u[3] = r57.y;
#else
      unsigned X0 = hi ? w0 : w2, X1 = hi ? w1 : w3;
      unsigned X2 = hi ? w4 : w6, X3 = hi ? w5 : w7;
      unsigned Y0 = __shfl_xor((int)X0, 32), Y1 = __shfl_xor((int)X1, 32);
      unsigned Y2 = __shfl_xor((int)X2, 32), Y3 = __shfl_xor((int)X3, 32);
      fe.u[0] = hi ? Y0 : w0; fe.u[1] = hi ? Y1 : w1;
      fe.u[2] = hi ? w2 : Y0; fe.u[3] = hi ? w3 : Y1;
      fo.u[0] = hi ? Y2 : w4; fo.u[1] = hi ? Y3 : w5;
      fo.u[2] = hi ? w6 : Y2; fo.u[3] = hi ? w7 : Y3;
#endif
#pragma unroll
      for (int half = 0; half < 2; ++half) {
        int kc = 2 * kg + half;
        bf16x8 pf = half ? fo.v : fe.v;
        bf16x8 vf0 = *reinterpret_cast<const bf16x8*>(&Vt[cur][fOff[kc]]);
        bf16x8 vf1 = *reinterpret_cast<const bf16x8*>(&Vt[cur][fOff[kc] + 2048]);
        accO0 = MFMA32(vf0, pf, accO0);
        accO1 = MFMA32(vf1, pf, accO1);
        accL = MFMA32(onesf, pf, accL);
      }
    }
    __builtin_amdgcn_s_setprio(0);

    if (more) {
      writeV(vnext, cur ^ 1);
      __syncthreads();
      cur ^= 1;
    }
  }

  // ---- epilogue ----
  float inv = 1.f / accL[0];
  bf16* yp = Y + head + (size_t)qrow * D;
#pragma unroll
  for (int g = 0; g < 4; ++g) {
    bf16x4 o0, o1;
#pragma unroll
    for (int i = 0; i < 4; ++i) {
      o0[i] = (bf16)(accO0[g * 4 + i] * inv);
      o1[i] = (bf16)(accO1[g * 4 + i] * inv);
    }
    *reinterpret_cast<bf16x4*>(yp + 8 * g + 4 * hi) = o0;
    *reinterpret_cast<bf16x4*>(yp + 32 + 8 * g + 4 * hi) = o1;
  }
}

// ---------------- launcher ----------------
extern "C" void kernel_launch(void* const* d_in, const int* in_sizes, int n_in,
                              void* d_out, int out_size, void* d_ws, size_t ws_size,
                              hipStream_t stream) {
  const float* x  = (const float*)d_in[0];
  const float* Wq = (const float*)d_in[1];
  const float* bq = (const float*)d_in[2];
  const float* Wk = (const float*)d_in[3];
  const float* bk = (const float*)d_in[4];
  const float* Wv = (const float*)d_in[5];
  const float* bv = (const float*)d_in[6];
  const float* Wo = (const float*)d_in[7];
  const float* bo = (const float*)d_in[8];
  float* out = (float*)d_out;

  constexpr int Bx = 2, S = 4096, Dd = 768;
  constexpr int M = Bx * S;
  constexpr size_t XB = (size_t)M * Dd;
  constexpr size_t WB = (size_t)Dd * Dd;

  char* ws = (char*)d_ws;
  bf16* xb = (bf16*)ws;
  bf16* Wb = (bf16*)(ws + 2 * XB);
  bf16* Qb = (bf16*)(ws + 2 * XB + 8 * WB);
  bf16* Kb = Qb + XB;
  bf16* Vb = Kb + XB;
  bf16* Yb = Vb + XB;

  cvt_all<<<2048, 256, 0, stream>>>(x, Wq, Wk, Wv, Wo, xb, Wb);

  gemm_bt<true><<<dim3(6, 64, 3), 256, 0, stream>>>(
      xb, Wb, bq, bk, bv, nullptr, Qb, M, Dd, Dd);

  attn32<<<dim3(1536), 128, 0, stream>>>(Qb, Kb, Vb, Yb);

  gemm_bt<false><<<dim3(6, 64, 1), 256, 0, stream>>>(
      Yb, Wb + 3 * WB, bo, bo, bo, out, nullptr, M, Dd, Dd);
}